// Round 1
// baseline (29647.318 us; speedup 1.0000x reference)
//
#include <hip/hip_runtime.h>
#include <math.h>

#define DIM 768
#define DEPTH 12
#define HEADS 12
#define DIM_HEAD 64
#define DIM_MLP 3072
#define PATCH 16
#define NUM_PATCHES 256
#define SEQ 257
#define NUM_CLASSES 1000
#define BATCH 32
#define SCALE 0.125f
#define EPS 1e-5f

// ---------------------------------------------------------------------------
// Patch embed: h[b,0,:] = cls_token + pos[0]; h[b,1+p,:] = x_patch @ conv_w +
// conv_b + pos[1+p].  One block per output row, 256 threads.
// ---------------------------------------------------------------------------
__global__ void patch_embed_kernel(const float* __restrict__ x,
                                   const float* __restrict__ conv_w,
                                   const float* __restrict__ conv_b,
                                   const float* __restrict__ pos,
                                   const float* __restrict__ cls_tok,
                                   float* __restrict__ h) {
    int row = blockIdx.x;            // 0 .. BATCH*SEQ-1
    int b = row / SEQ;
    int r = row % SEQ;
    int t = threadIdx.x;
    float* out = h + (long)row * DIM;
    if (r == 0) {
        for (int d = t; d < DIM; d += 256)
            out[d] = cls_tok[d] + pos[d];
        return;
    }
    int p = r - 1;
    const float* xp = x + (long)b * 4096 + p * PATCH;
    float xv[PATCH];
#pragma unroll
    for (int k = 0; k < PATCH; ++k) xv[k] = xp[k];
    for (int d = t; d < DIM; d += 256) {
        float acc = conv_b[d];
#pragma unroll
        for (int k = 0; k < PATCH; ++k)
            acc += xv[k] * conv_w[k * DIM + d];
        out[d] = acc + pos[(long)r * DIM + d];
    }
}

// ---------------------------------------------------------------------------
// LayerNorm over D=768.  One block (256 threads) per row.  in_stride lets us
// pick strided rows (cls extraction).  Output rows contiguous (stride DIM).
// ---------------------------------------------------------------------------
__global__ void layernorm_kernel(const float* __restrict__ in, long in_stride,
                                 const float* __restrict__ w,
                                 const float* __restrict__ bia,
                                 float* __restrict__ out) {
    __shared__ float red[8];
    long row = blockIdx.x;
    const float* src = in + row * in_stride;
    float* dst = out + row * DIM;
    int t = threadIdx.x;
    float v0 = src[t], v1 = src[t + 256], v2 = src[t + 512];
    float s = v0 + v1 + v2;
    float q = v0 * v0 + v1 * v1 + v2 * v2;
#pragma unroll
    for (int off = 32; off; off >>= 1) {
        s += __shfl_down(s, off);
        q += __shfl_down(q, off);
    }
    if ((t & 63) == 0) { red[t >> 6] = s; red[4 + (t >> 6)] = q; }
    __syncthreads();
    if (t == 0) {
        float ss = red[0] + red[1] + red[2] + red[3];
        float qq = red[4] + red[5] + red[6] + red[7];
        float mu = ss * (1.0f / DIM);
        float var = qq * (1.0f / DIM) - mu * mu;
        red[0] = mu;
        red[1] = rsqrtf(var + EPS);
    }
    __syncthreads();
    float mu = red[0], rstd = red[1];
    dst[t]       = (v0 - mu) * rstd * w[t]       + bia[t];
    dst[t + 256] = (v1 - mu) * rstd * w[t + 256] + bia[t + 256];
    dst[t + 512] = (v2 - mu) * rstd * w[t + 512] + bia[t + 512];
}

// ---------------------------------------------------------------------------
// Generic fp32 GEMM: C[M,N] = act(A[M,K] @ W[K,N] + bias) + resid
// ACT: 0 = none, 1 = exact GELU.  bias/resid may be null.
// 64x64 tile, 256 threads, 4x4 accumulators per thread, BK=16.
// Requires K % 16 == 0.  Handles ragged M and N.
// ---------------------------------------------------------------------------
template <int ACT>
__global__ void gemm_kernel(const float* __restrict__ A,
                            const float* __restrict__ W,
                            const float* __restrict__ bias,
                            const float* __restrict__ resid,
                            float* __restrict__ C,
                            int M, int N, int K) {
    __shared__ float As[16][65];
    __shared__ float Bs[16][65];
    int bm = blockIdx.x * 64, bn = blockIdx.y * 64;
    int t = threadIdx.x;
    int tx = t & 15, ty = t >> 4;
    float acc[4][4] = {};

    for (int k0 = 0; k0 < K; k0 += 16) {
        // A tile load: row = t>>2 (0..63), 4 k-cols at (t&3)*4.  Transposed
        // store into As[k][row].
        {
            int ar = bm + (t >> 2);
            int ac = k0 + (t & 3) * 4;
            float4 av = make_float4(0.f, 0.f, 0.f, 0.f);
            if (ar < M) av = *(const float4*)(A + (long)ar * K + ac);
            int kk = (t & 3) * 4, rr = t >> 2;
            As[kk + 0][rr] = av.x;
            As[kk + 1][rr] = av.y;
            As[kk + 2][rr] = av.z;
            As[kk + 3][rr] = av.w;
        }
        // W tile load: k-row = t>>4 (0..15), 4 n-cols at (t&15)*4.
        {
            int wr = k0 + (t >> 4);
            int wc = bn + (t & 15) * 4;
            float4 wv;
            if (wc + 3 < N) {
                wv = *(const float4*)(W + (long)wr * N + wc);
            } else {
                wv.x = (wc + 0 < N) ? W[(long)wr * N + wc + 0] : 0.f;
                wv.y = (wc + 1 < N) ? W[(long)wr * N + wc + 1] : 0.f;
                wv.z = (wc + 2 < N) ? W[(long)wr * N + wc + 2] : 0.f;
                wv.w = (wc + 3 < N) ? W[(long)wr * N + wc + 3] : 0.f;
            }
            int kr = t >> 4, nc = (t & 15) * 4;
            Bs[kr][nc + 0] = wv.x;
            Bs[kr][nc + 1] = wv.y;
            Bs[kr][nc + 2] = wv.z;
            Bs[kr][nc + 3] = wv.w;
        }
        __syncthreads();
#pragma unroll
        for (int kk = 0; kk < 16; ++kk) {
            float a0 = As[kk][ty * 4 + 0];
            float a1 = As[kk][ty * 4 + 1];
            float a2 = As[kk][ty * 4 + 2];
            float a3 = As[kk][ty * 4 + 3];
            float b0 = Bs[kk][tx];
            float b1 = Bs[kk][tx + 16];
            float b2 = Bs[kk][tx + 32];
            float b3 = Bs[kk][tx + 48];
            acc[0][0] += a0 * b0; acc[0][1] += a0 * b1; acc[0][2] += a0 * b2; acc[0][3] += a0 * b3;
            acc[1][0] += a1 * b0; acc[1][1] += a1 * b1; acc[1][2] += a1 * b2; acc[1][3] += a1 * b3;
            acc[2][0] += a2 * b0; acc[2][1] += a2 * b1; acc[2][2] += a2 * b2; acc[2][3] += a2 * b3;
            acc[3][0] += a3 * b0; acc[3][1] += a3 * b1; acc[3][2] += a3 * b2; acc[3][3] += a3 * b3;
        }
        __syncthreads();
    }

#pragma unroll
    for (int i = 0; i < 4; ++i) {
        int r = bm + ty * 4 + i;
        if (r >= M) continue;
#pragma unroll
        for (int j = 0; j < 4; ++j) {
            int c = bn + tx + 16 * j;
            if (c >= N) continue;
            float v = acc[i][j];
            if (bias) v += bias[c];
            if (ACT == 1) v = 0.5f * v * (1.0f + erff(v * 0.70710678118654752f));
            if (resid) v += resid[(long)r * N + c];
            C[(long)r * N + c] = v;
        }
    }
}

// ---------------------------------------------------------------------------
// Attention scores: S[bh,i,j] = SCALE * dot(q[b,i,h,:], k[b,j,h,:])
// qkv layout: [B, SEQ, 2304]; q at col h*64, k at 768+h*64, v at 1536+h*64.
// Block computes a 16x16 tile of S for one (b,h).
// ---------------------------------------------------------------------------
__global__ void attn_scores_kernel(const float* __restrict__ qkv,
                                   float* __restrict__ S) {
    __shared__ float Sq[16][65];
    __shared__ float Sk[16][65];
    int bh = blockIdx.z;
    int b = bh / HEADS, hh = bh % HEADS;
    int i0 = blockIdx.x * 16, j0 = blockIdx.y * 16;
    int t = threadIdx.x;
    int lr = t >> 4;             // 0..15 tile row
    int lc = (t & 15) * 4;       // 0,4,...,60

    float4 qv = make_float4(0.f, 0.f, 0.f, 0.f), kv = qv;
    int qi = i0 + lr, kj = j0 + lr;
    if (qi < SEQ) qv = *(const float4*)(qkv + ((long)(b * SEQ + qi)) * 2304 + hh * 64 + lc);
    if (kj < SEQ) kv = *(const float4*)(qkv + ((long)(b * SEQ + kj)) * 2304 + 768 + hh * 64 + lc);
    Sq[lr][lc + 0] = qv.x; Sq[lr][lc + 1] = qv.y; Sq[lr][lc + 2] = qv.z; Sq[lr][lc + 3] = qv.w;
    Sk[lr][lc + 0] = kv.x; Sk[lr][lc + 1] = kv.y; Sk[lr][lc + 2] = kv.z; Sk[lr][lc + 3] = kv.w;
    __syncthreads();

    int ti = t >> 4, tj = t & 15;
    float acc = 0.f;
#pragma unroll
    for (int d = 0; d < 64; ++d) acc += Sq[ti][d] * Sk[tj][d];
    int ii = i0 + ti, jj = j0 + tj;
    if (ii < SEQ && jj < SEQ)
        S[((long)bh * SEQ + ii) * SEQ + jj] = acc * SCALE;
}

// ---------------------------------------------------------------------------
// Row softmax over 257 elements, in place.  One block per row.
// ---------------------------------------------------------------------------
__global__ void softmax_kernel(float* __restrict__ S) {
    __shared__ float red[8];
    long row = blockIdx.x;
    float* p = S + row * SEQ;
    int t = threadIdx.x;
    float v0 = p[t];
    float v1 = (t == 0) ? p[256] : -3.4e38f;
    float m = fmaxf(v0, v1);
#pragma unroll
    for (int off = 32; off; off >>= 1) m = fmaxf(m, __shfl_down(m, off));
    if ((t & 63) == 0) red[t >> 6] = m;
    __syncthreads();
    if (t == 0) red[0] = fmaxf(fmaxf(red[0], red[1]), fmaxf(red[2], red[3]));
    __syncthreads();
    m = red[0];
    float e0 = expf(v0 - m);
    float e1 = (t == 0) ? expf(v1 - m) : 0.f;
    float s = e0 + e1;
#pragma unroll
    for (int off = 32; off; off >>= 1) s += __shfl_down(s, off);
    if ((t & 63) == 0) red[4 + (t >> 6)] = s;
    __syncthreads();
    if (t == 0) red[4] = red[4] + red[5] + red[6] + red[7];
    __syncthreads();
    float inv = 1.0f / red[4];
    p[t] = e0 * inv;
    if (t == 0) p[256] = e1 * inv;
}

// ---------------------------------------------------------------------------
// o[b,i,h*64+d] = sum_j S[bh,i,j] * v[b,j,h].  Block computes 16 rows x 64 d
// for one (b,h); K loop over j in chunks of 32.
// ---------------------------------------------------------------------------
__global__ void attn_av_kernel(const float* __restrict__ S,
                               const float* __restrict__ qkv,
                               float* __restrict__ o) {
    __shared__ float Ss[16][33];
    __shared__ float Vs[32][65];
    int bh = blockIdx.y;
    int b = bh / HEADS, hh = bh % HEADS;
    int i0 = blockIdx.x * 16;
    int t = threadIdx.x;
    int tx = t & 63;   // d
    int ty = t >> 6;   // row group 0..3
    float acc[4] = {0.f, 0.f, 0.f, 0.f};

    for (int j0 = 0; j0 < SEQ; j0 += 32) {
        // S tile 16x32: 2 scalars per thread (row base is odd-aligned; no float2)
        {
            int sr = t >> 4, sc = (t & 15) * 2;
            int ii = i0 + sr;
            float s0 = 0.f, s1 = 0.f;
            if (ii < SEQ) {
                long base = ((long)bh * SEQ + ii) * SEQ;
                int j1 = j0 + sc;
                if (j1 < SEQ) s0 = S[base + j1];
                if (j1 + 1 < SEQ) s1 = S[base + j1 + 1];
            }
            Ss[sr][sc] = s0;
            Ss[sr][sc + 1] = s1;
        }
        // V tile 32x64: 2 float4 per thread
        {
            int c0 = t * 2;
#pragma unroll
            for (int cc = 0; cc < 2; ++cc) {
                int c = c0 + cc;
                int vr = c >> 4, vc = (c & 15) * 4;
                int jv = j0 + vr;
                float4 vv = make_float4(0.f, 0.f, 0.f, 0.f);
                if (jv < SEQ)
                    vv = *(const float4*)(qkv + ((long)(b * SEQ + jv)) * 2304 + 1536 + hh * 64 + vc);
                Vs[vr][vc + 0] = vv.x; Vs[vr][vc + 1] = vv.y;
                Vs[vr][vc + 2] = vv.z; Vs[vr][vc + 3] = vv.w;
            }
        }
        __syncthreads();
#pragma unroll
        for (int jj = 0; jj < 32; ++jj) {
            float vv = Vs[jj][tx];
#pragma unroll
            for (int q = 0; q < 4; ++q)
                acc[q] += Ss[ty * 4 + q][jj] * vv;
        }
        __syncthreads();
    }
#pragma unroll
    for (int q = 0; q < 4; ++q) {
        int ii = i0 + ty * 4 + q;
        if (ii < SEQ)
            o[((long)(b * SEQ + ii)) * DIM + hh * 64 + tx] = acc[q];
    }
}

// ---------------------------------------------------------------------------
// Orchestration
// ---------------------------------------------------------------------------
extern "C" void kernel_launch(void* const* d_in, const int* in_sizes, int n_in,
                              void* d_out, int out_size, void* d_ws, size_t ws_size,
                              hipStream_t stream) {
    const float* x        = (const float*)d_in[0];
    const float* conv_w   = (const float*)d_in[1];
    const float* conv_b   = (const float*)d_in[2];
    const float* pos      = (const float*)d_in[3];
    const float* cls_tok  = (const float*)d_in[4];
    const float* ln1_w    = (const float*)d_in[5];
    const float* ln1_b    = (const float*)d_in[6];
    const float* qkv_w    = (const float*)d_in[7];
    const float* out_w    = (const float*)d_in[8];
    const float* out_b    = (const float*)d_in[9];
    const float* ln2_w    = (const float*)d_in[10];
    const float* ln2_b    = (const float*)d_in[11];
    const float* mlp_w1   = (const float*)d_in[12];
    const float* mlp_b1   = (const float*)d_in[13];
    const float* mlp_w2   = (const float*)d_in[14];
    const float* mlp_b2   = (const float*)d_in[15];
    const float* cls_ln_w = (const float*)d_in[16];
    const float* cls_ln_b = (const float*)d_in[17];
    const float* head_w   = (const float*)d_in[18];
    const float* head_b   = (const float*)d_in[19];
    float* out = (float*)d_out;

    const long ROWS = (long)BATCH * SEQ;  // 8224
    float* ws  = (float*)d_ws;
    float* h    = ws;                        // ROWS*768
    float* z    = h + ROWS * DIM;            // ROWS*768
    float* qkv  = z + ROWS * DIM;            // ROWS*2304
    float* o    = qkv + ROWS * 3 * DIM;      // ROWS*768
    float* S    = o + ROWS * DIM;            // B*H*SEQ*SEQ (25.36M fl, reused as mlp1)
    float* clsz = S + (long)BATCH * HEADS * SEQ * SEQ;  // 32*768
    // total ~253 MB of fp32 workspace

    patch_embed_kernel<<<(int)ROWS, 256, 0, stream>>>(x, conv_w, conv_b, pos, cls_tok, h);

    for (int l = 0; l < DEPTH; ++l) {
        const float* qw  = qkv_w  + (long)l * DIM * 3 * DIM;
        const float* ow  = out_w  + (long)l * DIM * DIM;
        const float* ob  = out_b  + (long)l * DIM;
        const float* w1  = mlp_w1 + (long)l * DIM * DIM_MLP;
        const float* b1  = mlp_b1 + (long)l * DIM_MLP;
        const float* w2  = mlp_w2 + (long)l * DIM_MLP * DIM;
        const float* b2  = mlp_b2 + (long)l * DIM;

        layernorm_kernel<<<(int)ROWS, 256, 0, stream>>>(h, DIM, ln1_w + (long)l * DIM,
                                                        ln1_b + (long)l * DIM, z);
        gemm_kernel<0><<<dim3(129, 36), 256, 0, stream>>>(z, qw, nullptr, nullptr, qkv,
                                                          (int)ROWS, 3 * DIM, DIM);
        attn_scores_kernel<<<dim3(17, 17, BATCH * HEADS), 256, 0, stream>>>(qkv, S);
        softmax_kernel<<<BATCH * HEADS * SEQ, 256, 0, stream>>>(S);
        attn_av_kernel<<<dim3(17, BATCH * HEADS), 256, 0, stream>>>(S, qkv, o);
        // h = o @ ow + ob + h   (in-place residual: each element read-then-written once)
        gemm_kernel<0><<<dim3(129, 12), 256, 0, stream>>>(o, ow, ob, h, h,
                                                          (int)ROWS, DIM, DIM);
        layernorm_kernel<<<(int)ROWS, 256, 0, stream>>>(h, DIM, ln2_w + (long)l * DIM,
                                                        ln2_b + (long)l * DIM, z);
        float* mlp1 = S;  // reuse scores buffer (25.26M < 25.36M floats)
        gemm_kernel<1><<<dim3(129, 48), 256, 0, stream>>>(z, w1, b1, nullptr, mlp1,
                                                          (int)ROWS, DIM_MLP, DIM);
        gemm_kernel<0><<<dim3(129, 12), 256, 0, stream>>>(mlp1, w2, b2, h, h,
                                                          (int)ROWS, DIM, DIM_MLP);
    }

    // cls token rows are strided SEQ*DIM apart
    layernorm_kernel<<<BATCH, 256, 0, stream>>>(h, (long)SEQ * DIM, cls_ln_w, cls_ln_b, clsz);
    gemm_kernel<0><<<dim3(1, 16), 256, 0, stream>>>(clsz, head_w, head_b, nullptr, out,
                                                    BATCH, NUM_CLASSES, DIM);
}

// Round 2
// 6571.332 us; speedup vs baseline: 4.5116x; 4.5116x over previous
//
#include <hip/hip_runtime.h>
#include <math.h>

#define DIM 768
#define DEPTH 12
#define HEADS 12
#define DIM_HEAD 64
#define DIM_MLP 3072
#define PATCH 16
#define NUM_PATCHES 256
#define SEQ 257
#define SEQP 320          // padded seq (multiple of 64)
#define NUM_CLASSES 1000
#define BATCH 32
#define SCALE 0.125f
#define EPS 1e-5f
#define ROWS 8224         // BATCH*SEQ
#define PAD_ROWS 8320     // 65*128

typedef short bf16x8 __attribute__((ext_vector_type(8)));
typedef float f32x4 __attribute__((ext_vector_type(4)));

__device__ inline unsigned short f2bf(float f) {
    union { float f; unsigned int u; } c; c.f = f;
    unsigned int u = c.u;
    return (unsigned short)((u + 0x7fffu + ((u >> 16) & 1u)) >> 16);
}
__device__ inline float bf2f(unsigned short b) {
    union { unsigned int u; float f; } c; c.u = ((unsigned int)b) << 16;
    return c.f;
}

// ---------------------------------------------------------------------------
// Patch embed (fp32, unchanged)
// ---------------------------------------------------------------------------
__global__ void patch_embed_kernel(const float* __restrict__ x,
                                   const float* __restrict__ conv_w,
                                   const float* __restrict__ conv_b,
                                   const float* __restrict__ pos,
                                   const float* __restrict__ cls_tok,
                                   float* __restrict__ h) {
    int row = blockIdx.x;
    int b = row / SEQ;
    int r = row % SEQ;
    int t = threadIdx.x;
    float* out = h + (long)row * DIM;
    if (r == 0) {
        for (int d = t; d < DIM; d += 256)
            out[d] = cls_tok[d] + pos[d];
        return;
    }
    int p = r - 1;
    const float* xp = x + (long)b * 4096 + p * PATCH;
    float xv[PATCH];
#pragma unroll
    for (int k = 0; k < PATCH; ++k) xv[k] = xp[k];
    for (int d = t; d < DIM; d += 256) {
        float acc = conv_b[d];
#pragma unroll
        for (int k = 0; k < PATCH; ++k)
            acc += xv[k] * conv_w[k * DIM + d];
        out[d] = acc + pos[(long)r * DIM + d];
    }
}

// ---------------------------------------------------------------------------
// LayerNorm (fp32 in, fp32 or bf16 out)
// ---------------------------------------------------------------------------
template <int OBF>
__global__ void layernorm_kernel(const float* __restrict__ in, long in_stride,
                                 const float* __restrict__ w,
                                 const float* __restrict__ bia,
                                 void* __restrict__ out) {
    __shared__ float red[8];
    long row = blockIdx.x;
    const float* src = in + row * in_stride;
    int t = threadIdx.x;
    float v0 = src[t], v1 = src[t + 256], v2 = src[t + 512];
    float s = v0 + v1 + v2;
    float q = v0 * v0 + v1 * v1 + v2 * v2;
#pragma unroll
    for (int off = 32; off; off >>= 1) {
        s += __shfl_down(s, off);
        q += __shfl_down(q, off);
    }
    if ((t & 63) == 0) { red[t >> 6] = s; red[4 + (t >> 6)] = q; }
    __syncthreads();
    if (t == 0) {
        float ss = red[0] + red[1] + red[2] + red[3];
        float qq = red[4] + red[5] + red[6] + red[7];
        float mu = ss * (1.0f / DIM);
        float var = qq * (1.0f / DIM) - mu * mu;
        red[0] = mu;
        red[1] = rsqrtf(var + EPS);
    }
    __syncthreads();
    float mu = red[0], rstd = red[1];
    float o0 = (v0 - mu) * rstd * w[t] + bia[t];
    float o1 = (v1 - mu) * rstd * w[t + 256] + bia[t + 256];
    float o2 = (v2 - mu) * rstd * w[t + 512] + bia[t + 512];
    if (OBF) {
        unsigned short* dst = (unsigned short*)out + row * DIM;
        dst[t] = f2bf(o0); dst[t + 256] = f2bf(o1); dst[t + 512] = f2bf(o2);
    } else {
        float* dst = (float*)out + row * DIM;
        dst[t] = o0; dst[t + 256] = o1; dst[t + 512] = o2;
    }
}

// ---------------------------------------------------------------------------
// Transpose + fp32->bf16: out[n][k] = bf16(in[k][n]).  K,N multiples of 32.
// ---------------------------------------------------------------------------
__global__ void transpose_bf16_kernel(const float* __restrict__ in,
                                      unsigned short* __restrict__ out,
                                      int K, int N) {
    __shared__ float tile[32][33];
    int k0 = blockIdx.x * 32, n0 = blockIdx.y * 32;
    int c = threadIdx.x & 31, r0 = threadIdx.x >> 5;  // r0: 0..7
#pragma unroll
    for (int rr = r0; rr < 32; rr += 8)
        tile[rr][c] = in[(long)(k0 + rr) * N + n0 + c];
    __syncthreads();
#pragma unroll
    for (int rr = r0; rr < 32; rr += 8)
        out[(long)(n0 + rr) * K + k0 + c] = f2bf(tile[c][rr]);
}

// ---------------------------------------------------------------------------
// bf16 MFMA GEMM (m97 structure): C = act(scale*(A @ Bt^T) + bias) (+resid)
//   A: bf16 [M][lda],  Bt: bf16 [N][ldb]  (B transposed, k-contiguous)
//   OBF=1 -> C bf16; OBF=0 -> C fp32 (+optional fp32 resid, may alias C)
//   Batched via blockIdx.z: off = (z/zdiv)*s1 + (z%zdiv)*s2 per operand.
//   BM,BN in {64,128}; block=256 threads=4 waves (2x2), wave tile BM/2 x BN/2.
//   K % 32 == 0.  Staging reads rows [bm, bm+BM) unconditionally -> A/Bt
//   must be readable (padded buffers); epilogue bounds-checks M,N.
// ---------------------------------------------------------------------------
template <int BM, int BN, int ACT, int OBF>
__global__ __launch_bounds__(256) void gemm_bf16_kernel(
    const unsigned short* __restrict__ A,
    const unsigned short* __restrict__ Bt,
    const float* __restrict__ bias,
    const float* __restrict__ resid,
    void* __restrict__ C,
    int M, int N, int K, int lda, int ldb, int ldc, float scale, int zdiv,
    long a_s1, long a_s2, long b_s1, long b_s2, long c_s1, long c_s2) {
    constexpr int FM = BM / 32, FN = BN / 32;
    __shared__ unsigned short As[BM * 32];
    __shared__ unsigned short Bs[BN * 32];
    const int tid = threadIdx.x;
    const int lane = tid & 63;
    const int w = tid >> 6;
    const int wr = w >> 1, wc = w & 1;
    const int z = blockIdx.z;
    const long aoff = (long)(z / zdiv) * a_s1 + (long)(z % zdiv) * a_s2;
    const long boff = (long)(z / zdiv) * b_s1 + (long)(z % zdiv) * b_s2;
    const long coff = (long)(z / zdiv) * c_s1 + (long)(z % zdiv) * c_s2;
    const int bm = blockIdx.x * BM, bn = blockIdx.y * BN;

    const unsigned short* Ab = A + aoff + (long)bm * lda;
    const unsigned short* Bb = Bt + boff + (long)bn * ldb;

    f32x4 acc[FM][FN] = {};

    for (int k0 = 0; k0 < K; k0 += 32) {
        // stage A tile [BM][32] and B tile [BN][32] linearly into LDS
#pragma unroll
        for (int c = tid; c < BM * 4; c += 256) {
            const unsigned short* g = Ab + (long)(c >> 2) * lda + k0 + (c & 3) * 8;
            __builtin_amdgcn_global_load_lds(
                (const __attribute__((address_space(1))) void*)g,
                (__attribute__((address_space(3))) void*)&As[c * 8], 16, 0, 0);
        }
#pragma unroll
        for (int c = tid; c < BN * 4; c += 256) {
            const unsigned short* g = Bb + (long)(c >> 2) * ldb + k0 + (c & 3) * 8;
            __builtin_amdgcn_global_load_lds(
                (const __attribute__((address_space(1))) void*)g,
                (__attribute__((address_space(3))) void*)&Bs[c * 8], 16, 0, 0);
        }
        __syncthreads();

        bf16x8 af[FM], bfr[FN];
#pragma unroll
        for (int m = 0; m < FM; ++m) {
            int r = wr * (BM / 2) + m * 16 + (lane & 15);
            af[m] = *(const bf16x8*)&As[r * 32 + (lane >> 4) * 8];
        }
#pragma unroll
        for (int n = 0; n < FN; ++n) {
            int cn = wc * (BN / 2) + n * 16 + (lane & 15);
            bfr[n] = *(const bf16x8*)&Bs[cn * 32 + (lane >> 4) * 8];
        }
#pragma unroll
        for (int m = 0; m < FM; ++m)
#pragma unroll
            for (int n = 0; n < FN; ++n)
                acc[m][n] = __builtin_amdgcn_mfma_f32_16x16x32_bf16(
                    af[m], bfr[n], acc[m][n], 0, 0, 0);
        __syncthreads();
    }

    // epilogue: C/D layout col=lane&15, row=(lane>>4)*4+j  [m89-verified]
#pragma unroll
    for (int m = 0; m < FM; ++m) {
#pragma unroll
        for (int n = 0; n < FN; ++n) {
            int gc = bn + wc * (BN / 2) + n * 16 + (lane & 15);
            if (gc >= N) continue;
            float bv = bias ? bias[gc] : 0.f;
#pragma unroll
            for (int j = 0; j < 4; ++j) {
                int gr = bm + wr * (BM / 2) + m * 16 + (lane >> 4) * 4 + j;
                if (gr >= M) continue;
                float v = acc[m][n][j] * scale + bv;
                if (ACT == 1) v = 0.5f * v * (1.0f + erff(v * 0.70710678118654752f));
                long ci = coff + (long)gr * ldc + gc;
                if (OBF) {
                    ((unsigned short*)C)[ci] = f2bf(v);
                } else {
                    if (resid) v += resid[ci];
                    ((float*)C)[ci] = v;
                }
            }
        }
    }
}

// ---------------------------------------------------------------------------
// Row softmax over bf16 scores: reads 257 cols, writes 320 (pads zeroed).
// One block per real row.  S layout: [384][SEQP][SEQP] bf16.
// ---------------------------------------------------------------------------
__global__ void softmax_bf16_kernel(unsigned short* __restrict__ S) {
    __shared__ float red[8];
    long r = blockIdx.x;               // 0 .. 384*257-1
    long zz = r / SEQ, ii = r % SEQ;
    unsigned short* p = S + (zz * SEQP + ii) * SEQP;
    int t = threadIdx.x;
    float v0 = bf2f(p[t]);
    float v1 = (t == 0) ? bf2f(p[256]) : -3.4e38f;
    float m = fmaxf(v0, v1);
#pragma unroll
    for (int off = 32; off; off >>= 1) m = fmaxf(m, __shfl_down(m, off));
    if ((t & 63) == 0) red[t >> 6] = m;
    __syncthreads();
    if (t == 0) red[0] = fmaxf(fmaxf(red[0], red[1]), fmaxf(red[2], red[3]));
    __syncthreads();
    m = red[0];
    float e0 = __expf(v0 - m);
    float e1 = (t == 0) ? __expf(v1 - m) : 0.f;
    float s = e0 + e1;
#pragma unroll
    for (int off = 32; off; off >>= 1) s += __shfl_down(s, off);
    if ((t & 63) == 0) red[4 + (t >> 6)] = s;
    __syncthreads();
    if (t == 0) red[4] = red[4] + red[5] + red[6] + red[7];
    __syncthreads();
    float inv = 1.0f / red[4];
    p[t] = f2bf(e0 * inv);
    if (t == 0) p[256] = f2bf(e1 * inv);
    if (t >= 1 && t < 64) p[256 + t] = 0;   // zero pad cols 257..319
}

// ---------------------------------------------------------------------------
// V repack: vT[z][d][j] = V[b,j,h,d] (bf16), zero for j >= SEQ.
// ---------------------------------------------------------------------------
__global__ void v_repack_kernel(const unsigned short* __restrict__ qkv_bf,
                                unsigned short* __restrict__ vT) {
    int z = blockIdx.x;
    int b = z / HEADS, hh = z % HEADS;
    for (int idx = threadIdx.x; idx < 64 * SEQP; idx += 256) {
        int d = idx / SEQP, j = idx % SEQP;
        unsigned short v = 0;
        if (j < SEQ)
            v = qkv_bf[((long)(b * SEQ + j)) * 2304 + 1536 + hh * 64 + d];
        vT[(long)z * 64 * SEQP + idx] = v;
    }
}

// ---------------------------------------------------------------------------
// fp32 GEMM (kept for the tiny classifier head)
// ---------------------------------------------------------------------------
__global__ void gemm_f32_kernel(const float* __restrict__ A,
                                const float* __restrict__ W,
                                const float* __restrict__ bias,
                                float* __restrict__ C,
                                int M, int N, int K) {
    __shared__ float As[16][65];
    __shared__ float Bs[16][65];
    int bm = blockIdx.x * 64, bn = blockIdx.y * 64;
    int t = threadIdx.x;
    int tx = t & 15, ty = t >> 4;
    float acc[4][4] = {};
    for (int k0 = 0; k0 < K; k0 += 16) {
        {
            int ar = bm + (t >> 2);
            int ac = k0 + (t & 3) * 4;
            float4 av = make_float4(0.f, 0.f, 0.f, 0.f);
            if (ar < M) av = *(const float4*)(A + (long)ar * K + ac);
            int kk = (t & 3) * 4, rr = t >> 2;
            As[kk + 0][rr] = av.x; As[kk + 1][rr] = av.y;
            As[kk + 2][rr] = av.z; As[kk + 3][rr] = av.w;
        }
        {
            int wr2 = k0 + (t >> 4);
            int wc2 = bn + (t & 15) * 4;
            float4 wv;
            wv.x = (wc2 + 0 < N) ? W[(long)wr2 * N + wc2 + 0] : 0.f;
            wv.y = (wc2 + 1 < N) ? W[(long)wr2 * N + wc2 + 1] : 0.f;
            wv.z = (wc2 + 2 < N) ? W[(long)wr2 * N + wc2 + 2] : 0.f;
            wv.w = (wc2 + 3 < N) ? W[(long)wr2 * N + wc2 + 3] : 0.f;
            int kr = t >> 4, nc = (t & 15) * 4;
            Bs[kr][nc + 0] = wv.x; Bs[kr][nc + 1] = wv.y;
            Bs[kr][nc + 2] = wv.z; Bs[kr][nc + 3] = wv.w;
        }
        __syncthreads();
#pragma unroll
        for (int kk = 0; kk < 16; ++kk) {
            float a0 = As[kk][ty * 4 + 0], a1 = As[kk][ty * 4 + 1];
            float a2 = As[kk][ty * 4 + 2], a3 = As[kk][ty * 4 + 3];
            float b0 = Bs[kk][tx], b1 = Bs[kk][tx + 16];
            float b2 = Bs[kk][tx + 32], b3 = Bs[kk][tx + 48];
            acc[0][0] += a0 * b0; acc[0][1] += a0 * b1; acc[0][2] += a0 * b2; acc[0][3] += a0 * b3;
            acc[1][0] += a1 * b0; acc[1][1] += a1 * b1; acc[1][2] += a1 * b2; acc[1][3] += a1 * b3;
            acc[2][0] += a2 * b0; acc[2][1] += a2 * b1; acc[2][2] += a2 * b2; acc[2][3] += a2 * b3;
            acc[3][0] += a3 * b0; acc[3][1] += a3 * b1; acc[3][2] += a3 * b2; acc[3][3] += a3 * b3;
        }
        __syncthreads();
    }
#pragma unroll
    for (int i = 0; i < 4; ++i) {
        int r = bm + ty * 4 + i;
        if (r >= M) continue;
#pragma unroll
        for (int j = 0; j < 4; ++j) {
            int c = bn + tx + 16 * j;
            if (c >= N) continue;
            C[(long)r * N + c] = acc[i][j] + (bias ? bias[c] : 0.f);
        }
    }
}

// ---------------------------------------------------------------------------
// Orchestration
// ---------------------------------------------------------------------------
extern "C" void kernel_launch(void* const* d_in, const int* in_sizes, int n_in,
                              void* d_out, int out_size, void* d_ws, size_t ws_size,
                              hipStream_t stream) {
    const float* x        = (const float*)d_in[0];
    const float* conv_w   = (const float*)d_in[1];
    const float* conv_b   = (const float*)d_in[2];
    const float* pos      = (const float*)d_in[3];
    const float* cls_tok  = (const float*)d_in[4];
    const float* ln1_w    = (const float*)d_in[5];
    const float* ln1_b    = (const float*)d_in[6];
    const float* qkv_w    = (const float*)d_in[7];
    const float* out_w    = (const float*)d_in[8];
    const float* out_b    = (const float*)d_in[9];
    const float* ln2_w    = (const float*)d_in[10];
    const float* ln2_b    = (const float*)d_in[11];
    const float* mlp_w1   = (const float*)d_in[12];
    const float* mlp_b1   = (const float*)d_in[13];
    const float* mlp_w2   = (const float*)d_in[14];
    const float* mlp_b2   = (const float*)d_in[15];
    const float* cls_ln_w = (const float*)d_in[16];
    const float* cls_ln_b = (const float*)d_in[17];
    const float* head_w   = (const float*)d_in[18];
    const float* head_b   = (const float*)d_in[19];
    float* out = (float*)d_out;

    char* cur = (char*)d_ws;
    auto alloc = [&](size_t bytes) {
        void* p = cur; cur += (bytes + 255) & ~(size_t)255; return p;
    };
    float*          h      = (float*)alloc((size_t)PAD_ROWS * DIM * 4);
    unsigned short* z_bf   = (unsigned short*)alloc((size_t)PAD_ROWS * DIM * 2);
    unsigned short* qkv_bf = (unsigned short*)alloc((size_t)PAD_ROWS * 3 * DIM * 2);
    unsigned short* o_bf   = (unsigned short*)alloc((size_t)PAD_ROWS * DIM * 2);
    unsigned short* S      = (unsigned short*)alloc((size_t)384 * SEQP * SEQP * 2);
    unsigned short* m1     = S;  // MLP hidden aliases S (51.1MB <= 78.6MB)
    unsigned short* vT     = (unsigned short*)alloc((size_t)384 * 64 * SEQP * 2);
    unsigned short* qkvwT  = (unsigned short*)alloc((size_t)2304 * 768 * 2);
    unsigned short* owT    = (unsigned short*)alloc((size_t)768 * 768 * 2);
    unsigned short* w1T    = (unsigned short*)alloc((size_t)3072 * 768 * 2);
    unsigned short* w2T    = (unsigned short*)alloc((size_t)768 * 3072 * 2);
    float*          clsz   = (float*)alloc((size_t)BATCH * DIM * 4);

    patch_embed_kernel<<<ROWS, 256, 0, stream>>>(x, conv_w, conv_b, pos, cls_tok, h);

    for (int l = 0; l < DEPTH; ++l) {
        // per-layer weight transpose+convert (fp32 [K][N] -> bf16 [N][K])
        transpose_bf16_kernel<<<dim3(24, 72), 256, 0, stream>>>(
            qkv_w + (long)l * DIM * 3 * DIM, qkvwT, DIM, 3 * DIM);
        transpose_bf16_kernel<<<dim3(24, 24), 256, 0, stream>>>(
            out_w + (long)l * DIM * DIM, owT, DIM, DIM);
        transpose_bf16_kernel<<<dim3(24, 96), 256, 0, stream>>>(
            mlp_w1 + (long)l * DIM * DIM_MLP, w1T, DIM, DIM_MLP);
        transpose_bf16_kernel<<<dim3(96, 24), 256, 0, stream>>>(
            mlp_w2 + (long)l * DIM_MLP * DIM, w2T, DIM_MLP, DIM);

        layernorm_kernel<1><<<ROWS, 256, 0, stream>>>(
            h, DIM, ln1_w + (long)l * DIM, ln1_b + (long)l * DIM, z_bf);

        // qkv = z @ qkv_w   [8224 x 2304]
        gemm_bf16_kernel<128, 128, 0, 1><<<dim3(65, 18, 1), 256, 0, stream>>>(
            z_bf, qkvwT, nullptr, nullptr, qkv_bf,
            ROWS + 96, 3 * DIM, DIM, DIM, DIM, 3 * DIM, 1.0f, 1, 0, 0, 0, 0, 0, 0);

        // S = scale * Q @ K^T  per (b,h); padded 320x320, bf16 out
        gemm_bf16_kernel<64, 64, 0, 1><<<dim3(5, 5, BATCH * HEADS), 256, 0, stream>>>(
            qkv_bf, qkv_bf + 768, nullptr, nullptr, S,
            SEQP, SEQP, DIM_HEAD, 3 * DIM, 3 * DIM, SEQP, SCALE, HEADS,
            (long)SEQ * 3 * DIM, 64, (long)SEQ * 3 * DIM, 64,
            (long)HEADS * SEQP * SEQP, (long)SEQP * SEQP);

        softmax_bf16_kernel<<<BATCH * HEADS * SEQ, 256, 0, stream>>>(S);
        v_repack_kernel<<<BATCH * HEADS, 256, 0, stream>>>(qkv_bf, vT);

        // o = softmax(S) @ V   [257 x 64] per (b,h)
        gemm_bf16_kernel<64, 64, 0, 1><<<dim3(5, 1, BATCH * HEADS), 256, 0, stream>>>(
            S, vT, nullptr, nullptr, o_bf,
            SEQ, DIM_HEAD, SEQP, SEQP, SEQP, DIM, 1.0f, HEADS,
            (long)HEADS * SEQP * SEQP, (long)SEQP * SEQP,
            (long)HEADS * 64 * SEQP, (long)64 * SEQP,
            (long)SEQ * DIM, 64);

        // h = o @ out_w + out_b + h  (fp32, in-place residual)
        gemm_bf16_kernel<128, 128, 0, 0><<<dim3(65, 6, 1), 256, 0, stream>>>(
            o_bf, owT, out_b + (long)l * DIM, h, h,
            ROWS, DIM, DIM, DIM, DIM, DIM, 1.0f, 1, 0, 0, 0, 0, 0, 0);

        layernorm_kernel<1><<<ROWS, 256, 0, stream>>>(
            h, DIM, ln2_w + (long)l * DIM, ln2_b + (long)l * DIM, z_bf);

        // m1 = gelu(z @ w1 + b1)   [8224 x 3072] bf16
        gemm_bf16_kernel<128, 128, 1, 1><<<dim3(65, 24, 1), 256, 0, stream>>>(
            z_bf, w1T, mlp_b1 + (long)l * DIM_MLP, nullptr, m1,
            ROWS + 96, DIM_MLP, DIM, DIM, DIM, DIM_MLP, 1.0f, 1, 0, 0, 0, 0, 0, 0);

        // h = m1 @ w2 + b2 + h  (fp32, in-place residual)
        gemm_bf16_kernel<128, 128, 0, 0><<<dim3(65, 6, 1), 256, 0, stream>>>(
            m1, w2T, mlp_b2 + (long)l * DIM, h, h,
            ROWS, DIM, DIM_MLP, DIM_MLP, DIM_MLP, DIM, 1.0f, 1, 0, 0, 0, 0, 0, 0);
    }

    layernorm_kernel<0><<<BATCH, 256, 0, stream>>>(
        h, (long)SEQ * DIM, cls_ln_w, cls_ln_b, clsz);
    gemm_f32_kernel<<<dim3(1, 16), 256, 0, stream>>>(
        clsz, head_w, head_b, out, BATCH, NUM_CLASSES, DIM);
}

// Round 3
// 5998.749 us; speedup vs baseline: 4.9423x; 1.0955x over previous
//
#include <hip/hip_runtime.h>
#include <math.h>

#define DIM 768
#define DEPTH 12
#define HEADS 12
#define DIM_HEAD 64
#define DIM_MLP 3072
#define PATCH 16
#define NUM_PATCHES 256
#define SEQ 257
#define SEQP 320          // padded seq (multiple of 64)
#define NUM_CLASSES 1000
#define BATCH 32
#define SCALE 0.125f
#define EPS 1e-5f
#define ROWS 8224         // BATCH*SEQ
#define PAD_ROWS 8320     // 65*128

typedef short bf16x8 __attribute__((ext_vector_type(8)));
typedef float f32x4 __attribute__((ext_vector_type(4)));

__device__ inline unsigned short f2bf(float f) {
    union { float f; unsigned int u; } c; c.f = f;
    unsigned int u = c.u;
    return (unsigned short)((u + 0x7fffu + ((u >> 16) & 1u)) >> 16);
}
__device__ inline float bf2f(unsigned short b) {
    union { unsigned int u; float f; } c; c.u = ((unsigned int)b) << 16;
    return c.f;
}

// ---------------------------------------------------------------------------
// Patch embed (fp32)
// ---------------------------------------------------------------------------
__global__ void patch_embed_kernel(const float* __restrict__ x,
                                   const float* __restrict__ conv_w,
                                   const float* __restrict__ conv_b,
                                   const float* __restrict__ pos,
                                   const float* __restrict__ cls_tok,
                                   float* __restrict__ h) {
    int row = blockIdx.x;
    int b = row / SEQ;
    int r = row % SEQ;
    int t = threadIdx.x;
    float* out = h + (long)row * DIM;
    if (r == 0) {
        for (int d = t; d < DIM; d += 256)
            out[d] = cls_tok[d] + pos[d];
        return;
    }
    int p = r - 1;
    const float* xp = x + (long)b * 4096 + p * PATCH;
    float xv[PATCH];
#pragma unroll
    for (int k = 0; k < PATCH; ++k) xv[k] = xp[k];
    for (int d = t; d < DIM; d += 256) {
        float acc = conv_b[d];
#pragma unroll
        for (int k = 0; k < PATCH; ++k)
            acc += xv[k] * conv_w[k * DIM + d];
        out[d] = acc + pos[(long)r * DIM + d];
    }
}

// ---------------------------------------------------------------------------
// LayerNorm (fp32 in, fp32 or bf16 out)
// ---------------------------------------------------------------------------
template <int OBF>
__global__ void layernorm_kernel(const float* __restrict__ in, long in_stride,
                                 const float* __restrict__ w,
                                 const float* __restrict__ bia,
                                 void* __restrict__ out) {
    __shared__ float red[8];
    long row = blockIdx.x;
    const float* src = in + row * in_stride;
    int t = threadIdx.x;
    float v0 = src[t], v1 = src[t + 256], v2 = src[t + 512];
    float s = v0 + v1 + v2;
    float q = v0 * v0 + v1 * v1 + v2 * v2;
#pragma unroll
    for (int off = 32; off; off >>= 1) {
        s += __shfl_down(s, off);
        q += __shfl_down(q, off);
    }
    if ((t & 63) == 0) { red[t >> 6] = s; red[4 + (t >> 6)] = q; }
    __syncthreads();
    if (t == 0) {
        float ss = red[0] + red[1] + red[2] + red[3];
        float qq = red[4] + red[5] + red[6] + red[7];
        float mu = ss * (1.0f / DIM);
        float var = qq * (1.0f / DIM) - mu * mu;
        red[0] = mu;
        red[1] = rsqrtf(var + EPS);
    }
    __syncthreads();
    float mu = red[0], rstd = red[1];
    float o0 = (v0 - mu) * rstd * w[t] + bia[t];
    float o1 = (v1 - mu) * rstd * w[t + 256] + bia[t + 256];
    float o2 = (v2 - mu) * rstd * w[t + 512] + bia[t + 512];
    if (OBF) {
        unsigned short* dst = (unsigned short*)out + row * DIM;
        dst[t] = f2bf(o0); dst[t + 256] = f2bf(o1); dst[t + 512] = f2bf(o2);
    } else {
        float* dst = (float*)out + row * DIM;
        dst[t] = o0; dst[t + 256] = o1; dst[t + 512] = o2;
    }
}

// ---------------------------------------------------------------------------
// Transpose + fp32->bf16: out[n][k] = bf16(in[k][n]).  K,N multiples of 32.
// ---------------------------------------------------------------------------
__global__ void transpose_bf16_kernel(const float* __restrict__ in,
                                      unsigned short* __restrict__ out,
                                      int K, int N) {
    __shared__ float tile[32][33];
    int k0 = blockIdx.x * 32, n0 = blockIdx.y * 32;
    int c = threadIdx.x & 31, r0 = threadIdx.x >> 5;
#pragma unroll
    for (int rr = r0; rr < 32; rr += 8)
        tile[rr][c] = in[(long)(k0 + rr) * N + n0 + c];
    __syncthreads();
#pragma unroll
    for (int rr = r0; rr < 32; rr += 8)
        out[(long)(n0 + rr) * K + k0 + c] = f2bf(tile[c][rr]);
}

// ---------------------------------------------------------------------------
// 8-phase 128x256 bf16 MFMA GEMM (T1+T2+T3+T4+T5 per CDNA4 guide).
//   C[M x GY*256] = act(A[M][lda] @ Bt[GY*256][ldb]^T + bias) (+resid)
//   512 threads = 8 waves (2 M x 4 N), per-wave 64x64, BK=64, dbuf LDS 96KB.
//   K = NK*64.  A rows [bm, bm+128) staged unconditionally (padded bufs);
//   epilogue bounds-checks M.  N must be multiple of 256.
// ---------------------------------------------------------------------------
#define MFMA16(d, a, b) d = __builtin_amdgcn_mfma_f32_16x16x32_bf16(a, b, d, 0, 0, 0)
#define SBAR() asm volatile("s_barrier" ::: "memory")
#define LGKM0() asm volatile("s_waitcnt lgkmcnt(0)" ::: "memory")

template <int NK, int ACT, int OBF>
__global__ __launch_bounds__(512, 2) void gemm8_kernel(
    const unsigned short* __restrict__ A,
    const unsigned short* __restrict__ Bt,
    const float* __restrict__ bias,
    const float* __restrict__ resid,
    void* __restrict__ C,
    int M, int GY, int lda, int ldb, int ldc) {
    __shared__ unsigned short sh[49152];   // 2 x (128*64 A + 256*64 B) bf16
    const int tid = threadIdx.x;
    const int lane = tid & 63;
    const int w = tid >> 6;
    const int wr = w >> 2;      // 0..1  (M half)
    const int wn = w & 3;       // 0..3  (N quarter)

    // T1: bijective XCD remap (m204), n-fast tile order
    const int nwg = gridDim.x;
    const int orig = blockIdx.x;
    const int q = nwg >> 3, r = nwg & 7;
    const int xcd = orig & 7, idx = orig >> 3;
    const int wg = (xcd < r ? xcd * (q + 1) : r * (q + 1) + (xcd - r) * q) + idx;
    const int bm = (wg / GY) * 128;
    const int bn = (wg % GY) * 256;

    const unsigned short* Ag = A + (long)bm * lda;
    const unsigned short* Bg = Bt + (long)bn * ldb;

    // T2 swizzle: LDS row stride 64 elems (128B); 16B-chunk index cb (0..7)
    // stored at cb, sourced/read at cb ^ (row&7).  Linear gload_lds dest.
    auto stageA = [&](int kt) {
        unsigned short* Lb = &sh[(kt & 1) * 24576];
#pragma unroll
        for (int u = 0; u < 2; ++u) {
            int c = tid + u * 512;
            int lr = c >> 3, cb = c & 7;
            const unsigned short* g = Ag + (long)lr * lda + kt * 64 + ((cb ^ (lr & 7)) << 3);
            __builtin_amdgcn_global_load_lds(
                (const __attribute__((address_space(1))) void*)g,
                (__attribute__((address_space(3))) void*)&Lb[lr * 64 + (cb << 3)], 16, 0, 0);
        }
    };
    auto stageB = [&](int kt, int half) {   // half 0: rows q*64+0..31, half 1: +32..63
        unsigned short* Lb = &sh[(kt & 1) * 24576 + 8192];
#pragma unroll
        for (int u = 0; u < 2; ++u) {
            int c = tid + u * 512;
            int lr = c >> 3, cb = c & 7;
            int br = ((lr >> 5) << 6) + (half << 5) + (lr & 31);
            const unsigned short* g = Bg + (long)br * ldb + kt * 64 + ((cb ^ (br & 7)) << 3);
            __builtin_amdgcn_global_load_lds(
                (const __attribute__((address_space(1))) void*)g,
                (__attribute__((address_space(3))) void*)&Lb[br * 64 + (cb << 3)], 16, 0, 0);
        }
    };
    auto ldA = [&](int p, int ms, int ks) {
        int row = wr * 64 + ms * 16 + (lane & 15);
        int cb = ks * 4 + (lane >> 4);
        return *(const bf16x8*)&sh[p * 24576 + row * 64 + ((cb ^ (row & 7)) << 3)];
    };
    auto ldB = [&](int p, int ns, int ks) {
        int br = wn * 64 + ns * 16 + (lane & 15);
        int cb = ks * 4 + (lane >> 4);
        return *(const bf16x8*)&sh[p * 24576 + 8192 + br * 64 + ((cb ^ (br & 7)) << 3)];
    };

    f32x4 acc[4][4] = {};

    // prologue: stage K-tiles 0 and 1 (3 units each: Bpa, Bpb, A)
    stageB(0, 0); stageB(0, 1); stageA(0);
    stageB(1, 0); stageB(1, 1); stageA(1);
    asm volatile("s_waitcnt vmcnt(6)" ::: "memory");  // kt0 landed (kt1's 6 in flight)
    SBAR();

#pragma unroll 2
    for (int kt = 0; kt < NK; ++kt) {
        const int p = kt & 1;
        // ---- Q0: reads A-half0 + B-half0; MFMA quadrant (mh0, nh0)
        bf16x8 aA = ldA(p, 0, 0), aB = ldA(p, 0, 1), aC = ldA(p, 1, 0), aD = ldA(p, 1, 1);
        bf16x8 b0A = ldB(p, 0, 0), b0B = ldB(p, 0, 1), b0C = ldB(p, 1, 0), b0D = ldB(p, 1, 1);
        SBAR(); LGKM0();
        __builtin_amdgcn_s_setprio(1);
        MFMA16(acc[0][0], aA, b0A); MFMA16(acc[0][0], aB, b0B);
        MFMA16(acc[0][1], aA, b0C); MFMA16(acc[0][1], aB, b0D);
        MFMA16(acc[1][0], aC, b0A); MFMA16(acc[1][0], aD, b0B);
        MFMA16(acc[1][1], aC, b0C); MFMA16(acc[1][1], aD, b0D);
        __builtin_amdgcn_s_setprio(0);
        SBAR();
        // ---- Q1: reads B-half1; stage Bpa(kt+2); MFMA (mh0, nh1)
        bf16x8 b1A = ldB(p, 2, 0), b1B = ldB(p, 2, 1), b1C = ldB(p, 3, 0), b1D = ldB(p, 3, 1);
        if (kt + 2 < NK) stageB(kt + 2, 0);
        SBAR(); LGKM0();
        __builtin_amdgcn_s_setprio(1);
        MFMA16(acc[0][2], aA, b1A); MFMA16(acc[0][2], aB, b1B);
        MFMA16(acc[0][3], aA, b1C); MFMA16(acc[0][3], aB, b1D);
        MFMA16(acc[1][2], aC, b1A); MFMA16(acc[1][2], aD, b1B);
        MFMA16(acc[1][3], aC, b1C); MFMA16(acc[1][3], aD, b1D);
        __builtin_amdgcn_s_setprio(0);
        SBAR();
        // ---- Q2: reads A-half1; stage Bpb(kt+2); MFMA (mh1, nh1)
        aA = ldA(p, 2, 0); aB = ldA(p, 2, 1); aC = ldA(p, 3, 0); aD = ldA(p, 3, 1);
        if (kt + 2 < NK) stageB(kt + 2, 1);
        SBAR(); LGKM0();
        __builtin_amdgcn_s_setprio(1);
        MFMA16(acc[2][2], aA, b1A); MFMA16(acc[2][2], aB, b1B);
        MFMA16(acc[2][3], aA, b1C); MFMA16(acc[2][3], aB, b1D);
        MFMA16(acc[3][2], aC, b1A); MFMA16(acc[3][2], aD, b1B);
        MFMA16(acc[3][3], aC, b1C); MFMA16(acc[3][3], aD, b1D);
        __builtin_amdgcn_s_setprio(0);
        SBAR();
        // ---- Q3: no reads (b0 regs alive); stage A(kt+2); MFMA (mh1, nh0)
        if (kt + 2 < NK) stageA(kt + 2);
        SBAR();
        __builtin_amdgcn_s_setprio(1);
        MFMA16(acc[2][0], aA, b0A); MFMA16(acc[2][0], aB, b0B);
        MFMA16(acc[2][1], aA, b0C); MFMA16(acc[2][1], aB, b0D);
        MFMA16(acc[3][0], aC, b0A); MFMA16(acc[3][0], aD, b0B);
        MFMA16(acc[3][1], aC, b0C); MFMA16(acc[3][1], aD, b0D);
        __builtin_amdgcn_s_setprio(0);
        // T4: counted vmcnt BEFORE the phase barrier (barrier publishes landings)
        if (kt + 2 < NK) {
            asm volatile("s_waitcnt vmcnt(6)" ::: "memory");
        } else if (kt + 1 < NK) {
            asm volatile("s_waitcnt vmcnt(0)" ::: "memory");
        }
        SBAR();
    }

    // epilogue: C/D layout col=lane&15, row=(lane>>4)*4+j
#pragma unroll
    for (int mi = 0; mi < 4; ++mi) {
        int gr0 = bm + wr * 64 + mi * 16 + (lane >> 4) * 4;
#pragma unroll
        for (int ni = 0; ni < 4; ++ni) {
            int gc = bn + wn * 64 + ni * 16 + (lane & 15);
            float bv = bias ? bias[gc] : 0.f;
#pragma unroll
            for (int j = 0; j < 4; ++j) {
                int gr = gr0 + j;
                if (gr >= M) continue;
                float v = acc[mi][ni][j] + bv;
                if (ACT) v = 0.5f * v * (1.0f + erff(v * 0.70710678118654752f));
                long ci = (long)gr * ldc + gc;
                if (OBF) {
                    ((unsigned short*)C)[ci] = f2bf(v);
                } else {
                    if (resid) v += resid[ci];
                    ((float*)C)[ci] = v;
                }
            }
        }
    }
}

// ---------------------------------------------------------------------------
// 2-phase bf16 MFMA GEMM (m97 structure) — kept for attention (small K).
// ---------------------------------------------------------------------------
template <int BM, int BN, int ACT, int OBF>
__global__ __launch_bounds__(256) void gemm_bf16_kernel(
    const unsigned short* __restrict__ A,
    const unsigned short* __restrict__ Bt,
    const float* __restrict__ bias,
    const float* __restrict__ resid,
    void* __restrict__ C,
    int M, int N, int K, int lda, int ldb, int ldc, float scale, int zdiv,
    long a_s1, long a_s2, long b_s1, long b_s2, long c_s1, long c_s2) {
    constexpr int FM = BM / 32, FN = BN / 32;
    __shared__ unsigned short As[BM * 32];
    __shared__ unsigned short Bs[BN * 32];
    const int tid = threadIdx.x;
    const int lane = tid & 63;
    const int w = tid >> 6;
    const int wr = w >> 1, wc = w & 1;
    const int z = blockIdx.z;
    const long aoff = (long)(z / zdiv) * a_s1 + (long)(z % zdiv) * a_s2;
    const long boff = (long)(z / zdiv) * b_s1 + (long)(z % zdiv) * b_s2;
    const long coff = (long)(z / zdiv) * c_s1 + (long)(z % zdiv) * c_s2;
    const int bm = blockIdx.x * BM, bn = blockIdx.y * BN;

    const unsigned short* Ab = A + aoff + (long)bm * lda;
    const unsigned short* Bb = Bt + boff + (long)bn * ldb;

    f32x4 acc[FM][FN] = {};

    for (int k0 = 0; k0 < K; k0 += 32) {
#pragma unroll
        for (int c = tid; c < BM * 4; c += 256) {
            const unsigned short* g = Ab + (long)(c >> 2) * lda + k0 + (c & 3) * 8;
            __builtin_amdgcn_global_load_lds(
                (const __attribute__((address_space(1))) void*)g,
                (__attribute__((address_space(3))) void*)&As[c * 8], 16, 0, 0);
        }
#pragma unroll
        for (int c = tid; c < BN * 4; c += 256) {
            const unsigned short* g = Bb + (long)(c >> 2) * ldb + k0 + (c & 3) * 8;
            __builtin_amdgcn_global_load_lds(
                (const __attribute__((address_space(1))) void*)g,
                (__attribute__((address_space(3))) void*)&Bs[c * 8], 16, 0, 0);
        }
        __syncthreads();

        bf16x8 af[FM], bfr[FN];
#pragma unroll
        for (int m = 0; m < FM; ++m) {
            int rr = wr * (BM / 2) + m * 16 + (lane & 15);
            af[m] = *(const bf16x8*)&As[rr * 32 + (lane >> 4) * 8];
        }
#pragma unroll
        for (int n = 0; n < FN; ++n) {
            int cn = wc * (BN / 2) + n * 16 + (lane & 15);
            bfr[n] = *(const bf16x8*)&Bs[cn * 32 + (lane >> 4) * 8];
        }
#pragma unroll
        for (int m = 0; m < FM; ++m)
#pragma unroll
            for (int n = 0; n < FN; ++n)
                acc[m][n] = __builtin_amdgcn_mfma_f32_16x16x32_bf16(
                    af[m], bfr[n], acc[m][n], 0, 0, 0);
        __syncthreads();
    }

#pragma unroll
    for (int m = 0; m < FM; ++m) {
#pragma unroll
        for (int n = 0; n < FN; ++n) {
            int gc = bn + wc * (BN / 2) + n * 16 + (lane & 15);
            if (gc >= N) continue;
            float bv = bias ? bias[gc] : 0.f;
#pragma unroll
            for (int j = 0; j < 4; ++j) {
                int gr = bm + wr * (BM / 2) + m * 16 + (lane >> 4) * 4 + j;
                if (gr >= M) continue;
                float v = acc[m][n][j] * scale + bv;
                if (ACT == 1) v = 0.5f * v * (1.0f + erff(v * 0.70710678118654752f));
                long ci = coff + (long)gr * ldc + gc;
                if (OBF) {
                    ((unsigned short*)C)[ci] = f2bf(v);
                } else {
                    if (resid) v += resid[ci];
                    ((float*)C)[ci] = v;
                }
            }
        }
    }
}

// ---------------------------------------------------------------------------
// Row softmax over bf16 scores (pads zeroed).
// ---------------------------------------------------------------------------
__global__ void softmax_bf16_kernel(unsigned short* __restrict__ S) {
    __shared__ float red[8];
    long r = blockIdx.x;
    long zz = r / SEQ, ii = r % SEQ;
    unsigned short* p = S + (zz * SEQP + ii) * SEQP;
    int t = threadIdx.x;
    float v0 = bf2f(p[t]);
    float v1 = (t == 0) ? bf2f(p[256]) : -3.4e38f;
    float m = fmaxf(v0, v1);
#pragma unroll
    for (int off = 32; off; off >>= 1) m = fmaxf(m, __shfl_down(m, off));
    if ((t & 63) == 0) red[t >> 6] = m;
    __syncthreads();
    if (t == 0) red[0] = fmaxf(fmaxf(red[0], red[1]), fmaxf(red[2], red[3]));
    __syncthreads();
    m = red[0];
    float e0 = __expf(v0 - m);
    float e1 = (t == 0) ? __expf(v1 - m) : 0.f;
    float s = e0 + e1;
#pragma unroll
    for (int off = 32; off; off >>= 1) s += __shfl_down(s, off);
    if ((t & 63) == 0) red[4 + (t >> 6)] = s;
    __syncthreads();
    if (t == 0) red[4] = red[4] + red[5] + red[6] + red[7];
    __syncthreads();
    float inv = 1.0f / red[4];
    p[t] = f2bf(e0 * inv);
    if (t == 0) p[256] = f2bf(e1 * inv);
    if (t >= 1 && t < 64) p[256 + t] = 0;
}

// ---------------------------------------------------------------------------
// V repack: vT[z][d][j] = V[b,j,h,d] (bf16), zero for j >= SEQ.
// ---------------------------------------------------------------------------
__global__ void v_repack_kernel(const unsigned short* __restrict__ qkv_bf,
                                unsigned short* __restrict__ vT) {
    int z = blockIdx.x;
    int b = z / HEADS, hh = z % HEADS;
    for (int idx = threadIdx.x; idx < 64 * SEQP; idx += 256) {
        int d = idx / SEQP, j = idx % SEQP;
        unsigned short v = 0;
        if (j < SEQ)
            v = qkv_bf[((long)(b * SEQ + j)) * 2304 + 1536 + hh * 64 + d];
        vT[(long)z * 64 * SEQP + idx] = v;
    }
}

// ---------------------------------------------------------------------------
// fp32 GEMM for the tiny classifier head
// ---------------------------------------------------------------------------
__global__ void gemm_f32_kernel(const float* __restrict__ A,
                                const float* __restrict__ W,
                                const float* __restrict__ bias,
                                float* __restrict__ C,
                                int M, int N, int K) {
    __shared__ float As[16][65];
    __shared__ float Bs[16][65];
    int bm = blockIdx.x * 64, bn = blockIdx.y * 64;
    int t = threadIdx.x;
    int tx = t & 15, ty = t >> 4;
    float acc[4][4] = {};
    for (int k0 = 0; k0 < K; k0 += 16) {
        {
            int ar = bm + (t >> 2);
            int ac = k0 + (t & 3) * 4;
            float4 av = make_float4(0.f, 0.f, 0.f, 0.f);
            if (ar < M) av = *(const float4*)(A + (long)ar * K + ac);
            int kk = (t & 3) * 4, rr = t >> 2;
            As[kk + 0][rr] = av.x; As[kk + 1][rr] = av.y;
            As[kk + 2][rr] = av.z; As[kk + 3][rr] = av.w;
        }
        {
            int wr2 = k0 + (t >> 4);
            int wc2 = bn + (t & 15) * 4;
            float4 wv;
            wv.x = (wc2 + 0 < N) ? W[(long)wr2 * N + wc2 + 0] : 0.f;
            wv.y = (wc2 + 1 < N) ? W[(long)wr2 * N + wc2 + 1] : 0.f;
            wv.z = (wc2 + 2 < N) ? W[(long)wr2 * N + wc2 + 2] : 0.f;
            wv.w = (wc2 + 3 < N) ? W[(long)wr2 * N + wc2 + 3] : 0.f;
            int kr = t >> 4, nc = (t & 15) * 4;
            Bs[kr][nc + 0] = wv.x; Bs[kr][nc + 1] = wv.y;
            Bs[kr][nc + 2] = wv.z; Bs[kr][nc + 3] = wv.w;
        }
        __syncthreads();
#pragma unroll
        for (int kk = 0; kk < 16; ++kk) {
            float a0 = As[kk][ty * 4 + 0], a1 = As[kk][ty * 4 + 1];
            float a2 = As[kk][ty * 4 + 2], a3 = As[kk][ty * 4 + 3];
            float b0 = Bs[kk][tx], b1 = Bs[kk][tx + 16];
            float b2 = Bs[kk][tx + 32], b3 = Bs[kk][tx + 48];
            acc[0][0] += a0 * b0; acc[0][1] += a0 * b1; acc[0][2] += a0 * b2; acc[0][3] += a0 * b3;
            acc[1][0] += a1 * b0; acc[1][1] += a1 * b1; acc[1][2] += a1 * b2; acc[1][3] += a1 * b3;
            acc[2][0] += a2 * b0; acc[2][1] += a2 * b1; acc[2][2] += a2 * b2; acc[2][3] += a2 * b3;
            acc[3][0] += a3 * b0; acc[3][1] += a3 * b1; acc[3][2] += a3 * b2; acc[3][3] += a3 * b3;
        }
        __syncthreads();
    }
#pragma unroll
    for (int i = 0; i < 4; ++i) {
        int r = bm + ty * 4 + i;
        if (r >= M) continue;
#pragma unroll
        for (int j = 0; j < 4; ++j) {
            int c = bn + tx + 16 * j;
            if (c >= N) continue;
            C[(long)r * N + c] = acc[i][j] + (bias ? bias[c] : 0.f);
        }
    }
}

// ---------------------------------------------------------------------------
// Orchestration
// ---------------------------------------------------------------------------
extern "C" void kernel_launch(void* const* d_in, const int* in_sizes, int n_in,
                              void* d_out, int out_size, void* d_ws, size_t ws_size,
                              hipStream_t stream) {
    const float* x        = (const float*)d_in[0];
    const float* conv_w   = (const float*)d_in[1];
    const float* conv_b   = (const float*)d_in[2];
    const float* pos      = (const float*)d_in[3];
    const float* cls_tok  = (const float*)d_in[4];
    const float* ln1_w    = (const float*)d_in[5];
    const float* ln1_b    = (const float*)d_in[6];
    const float* qkv_w    = (const float*)d_in[7];
    const float* out_w    = (const float*)d_in[8];
    const float* out_b    = (const float*)d_in[9];
    const float* ln2_w    = (const float*)d_in[10];
    const float* ln2_b    = (const float*)d_in[11];
    const float* mlp_w1   = (const float*)d_in[12];
    const float* mlp_b1   = (const float*)d_in[13];
    const float* mlp_w2   = (const float*)d_in[14];
    const float* mlp_b2   = (const float*)d_in[15];
    const float* cls_ln_w = (const float*)d_in[16];
    const float* cls_ln_b = (const float*)d_in[17];
    const float* head_w   = (const float*)d_in[18];
    const float* head_b   = (const float*)d_in[19];
    float* out = (float*)d_out;

    char* cur = (char*)d_ws;
    auto alloc = [&](size_t bytes) {
        void* p = cur; cur += (bytes + 255) & ~(size_t)255; return p;
    };
    float*          h      = (float*)alloc((size_t)PAD_ROWS * DIM * 4);
    unsigned short* z_bf   = (unsigned short*)alloc((size_t)PAD_ROWS * DIM * 2);
    unsigned short* qkv_bf = (unsigned short*)alloc((size_t)PAD_ROWS * 3 * DIM * 2);
    unsigned short* o_bf   = (unsigned short*)alloc((size_t)PAD_ROWS * DIM * 2);
    unsigned short* S      = (unsigned short*)alloc((size_t)384 * SEQP * SEQP * 2);
    unsigned short* m1     = S;  // MLP hidden aliases S (51.1MB <= 78.6MB)
    unsigned short* vT     = (unsigned short*)alloc((size_t)384 * 64 * SEQP * 2);
    unsigned short* qkvwT  = (unsigned short*)alloc((size_t)2304 * 768 * 2);
    unsigned short* owT    = (unsigned short*)alloc((size_t)768 * 768 * 2);
    unsigned short* w1T    = (unsigned short*)alloc((size_t)3072 * 768 * 2);
    unsigned short* w2T    = (unsigned short*)alloc((size_t)768 * 3072 * 2);
    float*          clsz   = (float*)alloc((size_t)BATCH * DIM * 4);

    patch_embed_kernel<<<ROWS, 256, 0, stream>>>(x, conv_w, conv_b, pos, cls_tok, h);

    for (int l = 0; l < DEPTH; ++l) {
        transpose_bf16_kernel<<<dim3(24, 72), 256, 0, stream>>>(
            qkv_w + (long)l * DIM * 3 * DIM, qkvwT, DIM, 3 * DIM);
        transpose_bf16_kernel<<<dim3(24, 24), 256, 0, stream>>>(
            out_w + (long)l * DIM * DIM, owT, DIM, DIM);
        transpose_bf16_kernel<<<dim3(24, 96), 256, 0, stream>>>(
            mlp_w1 + (long)l * DIM * DIM_MLP, w1T, DIM, DIM_MLP);
        transpose_bf16_kernel<<<dim3(96, 24), 256, 0, stream>>>(
            mlp_w2 + (long)l * DIM_MLP * DIM, w2T, DIM_MLP, DIM);

        layernorm_kernel<1><<<ROWS, 256, 0, stream>>>(
            h, DIM, ln1_w + (long)l * DIM, ln1_b + (long)l * DIM, z_bf);

        // qkv = z @ qkv_w   [8224 x 2304], K=768
        gemm8_kernel<12, 0, 1><<<65 * 9, 512, 0, stream>>>(
            z_bf, qkvwT, nullptr, nullptr, qkv_bf, ROWS, 9, DIM, DIM, 3 * DIM);

        // S = scale * Q @ K^T  per (b,h); padded 320x320, bf16 out
        gemm_bf16_kernel<64, 64, 0, 1><<<dim3(5, 5, BATCH * HEADS), 256, 0, stream>>>(
            qkv_bf, qkv_bf + 768, nullptr, nullptr, S,
            SEQP, SEQP, DIM_HEAD, 3 * DIM, 3 * DIM, SEQP, SCALE, HEADS,
            (long)SEQ * 3 * DIM, 64, (long)SEQ * 3 * DIM, 64,
            (long)HEADS * SEQP * SEQP, (long)SEQP * SEQP);

        softmax_bf16_kernel<<<BATCH * HEADS * SEQ, 256, 0, stream>>>(S);
        v_repack_kernel<<<BATCH * HEADS, 256, 0, stream>>>(qkv_bf, vT);

        // o = softmax(S) @ V   [257 x 64] per (b,h)
        gemm_bf16_kernel<64, 64, 0, 1><<<dim3(5, 1, BATCH * HEADS), 256, 0, stream>>>(
            S, vT, nullptr, nullptr, o_bf,
            SEQ, DIM_HEAD, SEQP, SEQP, SEQP, DIM, 1.0f, HEADS,
            (long)HEADS * SEQP * SEQP, (long)SEQP * SEQP,
            (long)HEADS * 64 * SEQP, (long)64 * SEQP,
            (long)SEQ * DIM, 64);

        // h = o @ out_w + out_b + h   (fp32, in-place residual), K=768
        gemm8_kernel<12, 0, 0><<<65 * 3, 512, 0, stream>>>(
            o_bf, owT, out_b + (long)l * DIM, h, h, ROWS, 3, DIM, DIM, DIM);

        layernorm_kernel<1><<<ROWS, 256, 0, stream>>>(
            h, DIM, ln2_w + (long)l * DIM, ln2_b + (long)l * DIM, z_bf);

        // m1 = gelu(z @ w1 + b1)   [8224 x 3072], K=768
        gemm8_kernel<12, 1, 1><<<65 * 12, 512, 0, stream>>>(
            z_bf, w1T, mlp_b1 + (long)l * DIM_MLP, nullptr, m1, ROWS, 12, DIM, DIM, DIM_MLP);

        // h = m1 @ w2 + b2 + h   (fp32, in-place residual), K=3072
        gemm8_kernel<48, 0, 0><<<65 * 3, 512, 0, stream>>>(
            m1, w2T, mlp_b2 + (long)l * DIM, h, h, ROWS, 3, DIM_MLP, DIM_MLP, DIM);
    }

    layernorm_kernel<0><<<BATCH, 256, 0, stream>>>(
        h, (long)SEQ * DIM, cls_ln_w, cls_ln_b, clsz);
    gemm_f32_kernel<<<dim3(1, 16), 256, 0, stream>>>(
        clsz, head_w, head_b, out, BATCH, NUM_CLASSES, DIM);
}

// Round 4
// 5375.658 us; speedup vs baseline: 5.5151x; 1.1159x over previous
//
#include <hip/hip_runtime.h>
#include <math.h>

#define DIM 768
#define DEPTH 12
#define HEADS 12
#define DIM_HEAD 64
#define DIM_MLP 3072
#define PATCH 16
#define NUM_PATCHES 256
#define SEQ 257
#define SEQP 320          // padded seq (multiple of 64)
#define NUM_CLASSES 1000
#define BATCH 32
#define SCALE 0.125f
#define EPS 1e-5f
#define ROWS 8224         // BATCH*SEQ
#define PAD_ROWS 8320     // 65*128
#define PAD_A 8448        // 33*256 (A-staging pad for 256-row tiles)

typedef short bf16x8 __attribute__((ext_vector_type(8)));
typedef float f32x4 __attribute__((ext_vector_type(4)));

__device__ inline unsigned short f2bf(float f) {
    union { float f; unsigned int u; } c; c.f = f;
    unsigned int u = c.u;
    return (unsigned short)((u + 0x7fffu + ((u >> 16) & 1u)) >> 16);
}
__device__ inline float bf2f(unsigned short b) {
    union { unsigned int u; float f; } c; c.u = ((unsigned int)b) << 16;
    return c.f;
}

#define MFMA16(d, a, b) d = __builtin_amdgcn_mfma_f32_16x16x32_bf16(a, b, d, 0, 0, 0)
#define SBAR() asm volatile("s_barrier" ::: "memory")
#define LGKM0() asm volatile("s_waitcnt lgkmcnt(0)" ::: "memory")

// ---------------------------------------------------------------------------
// Patch embed (fp32)
// ---------------------------------------------------------------------------
__global__ void patch_embed_kernel(const float* __restrict__ x,
                                   const float* __restrict__ conv_w,
                                   const float* __restrict__ conv_b,
                                   const float* __restrict__ pos,
                                   const float* __restrict__ cls_tok,
                                   float* __restrict__ h) {
    int row = blockIdx.x;
    int b = row / SEQ;
    int r = row % SEQ;
    int t = threadIdx.x;
    float* out = h + (long)row * DIM;
    if (r == 0) {
        for (int d = t; d < DIM; d += 256)
            out[d] = cls_tok[d] + pos[d];
        return;
    }
    int p = r - 1;
    const float* xp = x + (long)b * 4096 + p * PATCH;
    float xv[PATCH];
#pragma unroll
    for (int k = 0; k < PATCH; ++k) xv[k] = xp[k];
    for (int d = t; d < DIM; d += 256) {
        float acc = conv_b[d];
#pragma unroll
        for (int k = 0; k < PATCH; ++k)
            acc += xv[k] * conv_w[k * DIM + d];
        out[d] = acc + pos[(long)r * DIM + d];
    }
}

// ---------------------------------------------------------------------------
// LayerNorm (fp32 in, fp32 or bf16 out)
// ---------------------------------------------------------------------------
template <int OBF>
__global__ void layernorm_kernel(const float* __restrict__ in, long in_stride,
                                 const float* __restrict__ w,
                                 const float* __restrict__ bia,
                                 void* __restrict__ out) {
    __shared__ float red[8];
    long row = blockIdx.x;
    const float* src = in + row * in_stride;
    int t = threadIdx.x;
    float v0 = src[t], v1 = src[t + 256], v2 = src[t + 512];
    float s = v0 + v1 + v2;
    float q = v0 * v0 + v1 * v1 + v2 * v2;
#pragma unroll
    for (int off = 32; off; off >>= 1) {
        s += __shfl_down(s, off);
        q += __shfl_down(q, off);
    }
    if ((t & 63) == 0) { red[t >> 6] = s; red[4 + (t >> 6)] = q; }
    __syncthreads();
    if (t == 0) {
        float ss = red[0] + red[1] + red[2] + red[3];
        float qq = red[4] + red[5] + red[6] + red[7];
        float mu = ss * (1.0f / DIM);
        float var = qq * (1.0f / DIM) - mu * mu;
        red[0] = mu;
        red[1] = rsqrtf(var + EPS);
    }
    __syncthreads();
    float mu = red[0], rstd = red[1];
    float o0 = (v0 - mu) * rstd * w[t] + bia[t];
    float o1 = (v1 - mu) * rstd * w[t + 256] + bia[t + 256];
    float o2 = (v2 - mu) * rstd * w[t + 512] + bia[t + 512];
    if (OBF) {
        unsigned short* dst = (unsigned short*)out + row * DIM;
        dst[t] = f2bf(o0); dst[t + 256] = f2bf(o1); dst[t + 512] = f2bf(o2);
    } else {
        float* dst = (float*)out + row * DIM;
        dst[t] = o0; dst[t + 256] = o1; dst[t + 512] = o2;
    }
}

// ---------------------------------------------------------------------------
// Transpose + fp32->bf16: out[n][k] = bf16(in[k][n]).  K,N multiples of 32.
// ---------------------------------------------------------------------------
__global__ void transpose_bf16_kernel(const float* __restrict__ in,
                                      unsigned short* __restrict__ out,
                                      int K, int N) {
    __shared__ float tile[32][33];
    int k0 = blockIdx.x * 32, n0 = blockIdx.y * 32;
    int c = threadIdx.x & 31, r0 = threadIdx.x >> 5;
#pragma unroll
    for (int rr = r0; rr < 32; rr += 8)
        tile[rr][c] = in[(long)(k0 + rr) * N + n0 + c];
    __syncthreads();
#pragma unroll
    for (int rr = r0; rr < 32; rr += 8)
        out[(long)(n0 + rr) * K + k0 + c] = f2bf(tile[c][rr]);
}

// ---------------------------------------------------------------------------
// 256x256 8-phase bf16 MFMA GEMM (m201 geometry: 8 waves, per-wave 128x64,
// 16 MFMA/phase, BK=64, 128KB dbuf LDS, T1+T2+T4+T5).
//   C[M x GY*256] = act(A[M][lda] @ Bt[GY*256][ldb]^T + bias), bf16 out.
//   A rows [bm, bm+256) staged unconditionally -> A buffer padded to
//   ceil(M/256)*256 rows; epilogue bounds-checks M.
// Stage-unit race rule: each LDS region is staged (for kt+2) only in a phase
// AFTER the phase whose barrier certifies its last ds_read this kt.
// ---------------------------------------------------------------------------
template <int NK, int ACT>
__global__ __launch_bounds__(512, 2) void gemm256_kernel(
    const unsigned short* __restrict__ A,
    const unsigned short* __restrict__ Bt,
    const float* __restrict__ bias,
    unsigned short* __restrict__ C,
    int M, int GY, int lda, int ldb, int ldc) {
    __shared__ unsigned short sh[65536];   // 2 x (256*64 A + 256*64 B)
    const int tid = threadIdx.x;
    const int lane = tid & 63;
    const int w = tid >> 6;
    const int wr = w >> 2;      // 0..1  M half (128 rows each)
    const int wn = w & 3;       // 0..3  N quarter (64 cols each)

    // T1: bijective XCD remap, n-fast tile order
    const int nwg = gridDim.x;
    const int orig = blockIdx.x;
    const int q = nwg >> 3, r = nwg & 7;
    const int xcd = orig & 7, idx = orig >> 3;
    const int wg = (xcd < r ? xcd * (q + 1) : r * (q + 1) + (xcd - r) * q) + idx;
    const int bm = (wg / GY) * 256;
    const int bn = (wg % GY) * 256;

    const unsigned short* Ag = A + (long)bm * lda;
    const unsigned short* Bg = Bt + (long)bn * ldb;

    // T2 swizzle: row stride 64 elems (128B); 16B chunk cb stored linear,
    // global source and ds_read both use cb ^ (row&7).
    auto stageA = [&](int kt, int half) {   // half: each 128-row group's 64-row half
        unsigned short* Lb = &sh[(kt & 1) * 32768];
#pragma unroll
        for (int u = 0; u < 2; ++u) {
            int c = tid + u * 512;
            int lr = c >> 3, cb = c & 7;
            int row = ((lr >> 6) << 7) + (half << 6) + (lr & 63);
            const unsigned short* g = Ag + (long)row * lda + kt * 64 + ((cb ^ (row & 7)) << 3);
            __builtin_amdgcn_global_load_lds(
                (const __attribute__((address_space(1))) void*)g,
                (__attribute__((address_space(3))) void*)&Lb[row * 64 + (cb << 3)], 16, 0, 0);
        }
    };
    auto stageB = [&](int kt, int half) {   // half: each 64-row group's 32-row half
        unsigned short* Lb = &sh[(kt & 1) * 32768 + 16384];
#pragma unroll
        for (int u = 0; u < 2; ++u) {
            int c = tid + u * 512;
            int lr = c >> 3, cb = c & 7;
            int row = ((lr >> 5) << 6) + (half << 5) + (lr & 31);
            const unsigned short* g = Bg + (long)row * ldb + kt * 64 + ((cb ^ (row & 7)) << 3);
            __builtin_amdgcn_global_load_lds(
                (const __attribute__((address_space(1))) void*)g,
                (__attribute__((address_space(3))) void*)&Lb[row * 64 + (cb << 3)], 16, 0, 0);
        }
    };
    auto ldA = [&](int p, int m, int ks) {   // m 0..7
        int row = wr * 128 + m * 16 + (lane & 15);
        int cb = ks * 4 + (lane >> 4);
        return *(const bf16x8*)&sh[p * 32768 + row * 64 + ((cb ^ (row & 7)) << 3)];
    };
    auto ldB = [&](int p, int n, int ks) {   // n 0..3
        int row = wn * 64 + n * 16 + (lane & 15);
        int cb = ks * 4 + (lane >> 4);
        return *(const bf16x8*)&sh[p * 32768 + 16384 + row * 64 + ((cb ^ (row & 7)) << 3)];
    };

    f32x4 acc[8][4] = {};

    // prologue: fully stage K-tiles 0 and 1 (8 gload instr each per thread-pair)
    stageA(0, 0); stageA(0, 1); stageB(0, 0); stageB(0, 1);
    stageA(1, 0); stageA(1, 1); stageB(1, 0); stageB(1, 1);
    asm volatile("s_waitcnt vmcnt(8)" ::: "memory");   // kt0 landed, kt1 in flight
    SBAR();

    bf16x8 a[4][2], b01[2][2], b23[2][2];
    for (int kt = 0; kt < NK; ++kt) {
        const int p = kt & 1;
        // ---- Q0: read A m0-3 (both k) + B n0-1 (both k); MFMA m0-3 x n0-1
#pragma unroll
        for (int m = 0; m < 4; ++m) { a[m][0] = ldA(p, m, 0); a[m][1] = ldA(p, m, 1); }
#pragma unroll
        for (int n = 0; n < 2; ++n) { b01[n][0] = ldB(p, n, 0); b01[n][1] = ldB(p, n, 1); }
        SBAR(); LGKM0();
        __builtin_amdgcn_s_setprio(1);
#pragma unroll
        for (int m = 0; m < 4; ++m)
#pragma unroll
            for (int n = 0; n < 2; ++n) {
                MFMA16(acc[m][n], a[m][0], b01[n][0]);
                MFMA16(acc[m][n], a[m][1], b01[n][1]);
            }
        __builtin_amdgcn_s_setprio(0);
        SBAR();
        // ---- Q1: read B n2-3; stage A-mh0(kt+2) [A-mh0 fully read in Q0]
#pragma unroll
        for (int n = 0; n < 2; ++n) { b23[n][0] = ldB(p, n + 2, 0); b23[n][1] = ldB(p, n + 2, 1); }
        if (kt + 2 < NK) stageA(kt + 2, 0);
        SBAR(); LGKM0();
        __builtin_amdgcn_s_setprio(1);
#pragma unroll
        for (int m = 0; m < 4; ++m)
#pragma unroll
            for (int n = 0; n < 2; ++n) {
                MFMA16(acc[m][n + 2], a[m][0], b23[n][0]);
                MFMA16(acc[m][n + 2], a[m][1], b23[n][1]);
            }
        __builtin_amdgcn_s_setprio(0);
        SBAR();
        // ---- Q2: read A m4-7; stage B-nh0(kt+2) [B-nh0 fully read in Q0]
#pragma unroll
        for (int m = 0; m < 4; ++m) { a[m][0] = ldA(p, m + 4, 0); a[m][1] = ldA(p, m + 4, 1); }
        if (kt + 2 < NK) stageB(kt + 2, 0);
        SBAR(); LGKM0();
        __builtin_amdgcn_s_setprio(1);
#pragma unroll
        for (int m = 0; m < 4; ++m)
#pragma unroll
            for (int n = 0; n < 2; ++n) {
                MFMA16(acc[m + 4][n + 2], a[m][0], b23[n][0]);
                MFMA16(acc[m + 4][n + 2], a[m][1], b23[n][1]);
            }
        __builtin_amdgcn_s_setprio(0);
        SBAR();
        // ---- Q3: stage A-mh1 + B-nh1 (kt+2) [read in Q2 / Q1]; MFMA m4-7 x n0-1
        if (kt + 2 < NK) { stageA(kt + 2, 1); stageB(kt + 2, 1); }
        SBAR();
        __builtin_amdgcn_s_setprio(1);
#pragma unroll
        for (int m = 0; m < 4; ++m)
#pragma unroll
            for (int n = 0; n < 2; ++n) {
                MFMA16(acc[m + 4][n], a[m][0], b01[n][0]);
                MFMA16(acc[m + 4][n], a[m][1], b01[n][1]);
            }
        __builtin_amdgcn_s_setprio(0);
        // T4: counted vmcnt once per K-tile, never 0 in steady state
        if (kt + 2 < NK) {
            asm volatile("s_waitcnt vmcnt(8)" ::: "memory");
        } else if (kt + 1 < NK) {
            asm volatile("s_waitcnt vmcnt(0)" ::: "memory");
        }
        SBAR();
    }

    // epilogue: C/D layout col=lane&15, row=(lane>>4)*4+j
#pragma unroll
    for (int mi = 0; mi < 8; ++mi) {
        int gr0 = bm + wr * 128 + mi * 16 + (lane >> 4) * 4;
#pragma unroll
        for (int ni = 0; ni < 4; ++ni) {
            int gc = bn + wn * 64 + ni * 16 + (lane & 15);
            float bv = bias ? bias[gc] : 0.f;
#pragma unroll
            for (int j = 0; j < 4; ++j) {
                int gr = gr0 + j;
                if (gr >= M) continue;
                float v = acc[mi][ni][j] + bv;
                if (ACT) v = 0.5f * v * (1.0f + erff(v * 0.70710678118654752f));
                C[(long)gr * ldc + gc] = f2bf(v);
            }
        }
    }
}

// ---------------------------------------------------------------------------
// 8-phase 128x256 bf16 MFMA GEMM (round-3, proven) — for proj & mlp2 (N=768).
// ---------------------------------------------------------------------------
template <int NK, int ACT, int OBF>
__global__ __launch_bounds__(512, 2) void gemm8_kernel(
    const unsigned short* __restrict__ A,
    const unsigned short* __restrict__ Bt,
    const float* __restrict__ bias,
    const float* __restrict__ resid,
    void* __restrict__ C,
    int M, int GY, int lda, int ldb, int ldc) {
    __shared__ unsigned short sh[49152];
    const int tid = threadIdx.x;
    const int lane = tid & 63;
    const int w = tid >> 6;
    const int wr = w >> 2;
    const int wn = w & 3;

    const int nwg = gridDim.x;
    const int orig = blockIdx.x;
    const int q = nwg >> 3, r = nwg & 7;
    const int xcd = orig & 7, idx = orig >> 3;
    const int wg = (xcd < r ? xcd * (q + 1) : r * (q + 1) + (xcd - r) * q) + idx;
    const int bm = (wg / GY) * 128;
    const int bn = (wg % GY) * 256;

    const unsigned short* Ag = A + (long)bm * lda;
    const unsigned short* Bg = Bt + (long)bn * ldb;

    auto stageA = [&](int kt) {
        unsigned short* Lb = &sh[(kt & 1) * 24576];
#pragma unroll
        for (int u = 0; u < 2; ++u) {
            int c = tid + u * 512;
            int lr = c >> 3, cb = c & 7;
            const unsigned short* g = Ag + (long)lr * lda + kt * 64 + ((cb ^ (lr & 7)) << 3);
            __builtin_amdgcn_global_load_lds(
                (const __attribute__((address_space(1))) void*)g,
                (__attribute__((address_space(3))) void*)&Lb[lr * 64 + (cb << 3)], 16, 0, 0);
        }
    };
    auto stageB = [&](int kt, int half) {
        unsigned short* Lb = &sh[(kt & 1) * 24576 + 8192];
#pragma unroll
        for (int u = 0; u < 2; ++u) {
            int c = tid + u * 512;
            int lr = c >> 3, cb = c & 7;
            int br = ((lr >> 5) << 6) + (half << 5) + (lr & 31);
            const unsigned short* g = Bg + (long)br * ldb + kt * 64 + ((cb ^ (br & 7)) << 3);
            __builtin_amdgcn_global_load_lds(
                (const __attribute__((address_space(1))) void*)g,
                (__attribute__((address_space(3))) void*)&Lb[br * 64 + (cb << 3)], 16, 0, 0);
        }
    };
    auto ldA = [&](int p, int ms, int ks) {
        int row = wr * 64 + ms * 16 + (lane & 15);
        int cb = ks * 4 + (lane >> 4);
        return *(const bf16x8*)&sh[p * 24576 + row * 64 + ((cb ^ (row & 7)) << 3)];
    };
    auto ldB = [&](int p, int ns, int ks) {
        int br = wn * 64 + ns * 16 + (lane & 15);
        int cb = ks * 4 + (lane >> 4);
        return *(const bf16x8*)&sh[p * 24576 + 8192 + br * 64 + ((cb ^ (br & 7)) << 3)];
    };

    f32x4 acc[4][4] = {};

    stageB(0, 0); stageB(0, 1); stageA(0);
    stageB(1, 0); stageB(1, 1); stageA(1);
    asm volatile("s_waitcnt vmcnt(6)" ::: "memory");
    SBAR();

#pragma unroll 2
    for (int kt = 0; kt < NK; ++kt) {
        const int p = kt & 1;
        bf16x8 aA = ldA(p, 0, 0), aB = ldA(p, 0, 1), aC = ldA(p, 1, 0), aD = ldA(p, 1, 1);
        bf16x8 b0A = ldB(p, 0, 0), b0B = ldB(p, 0, 1), b0C = ldB(p, 1, 0), b0D = ldB(p, 1, 1);
        SBAR(); LGKM0();
        __builtin_amdgcn_s_setprio(1);
        MFMA16(acc[0][0], aA, b0A); MFMA16(acc[0][0], aB, b0B);
        MFMA16(acc[0][1], aA, b0C); MFMA16(acc[0][1], aB, b0D);
        MFMA16(acc[1][0], aC, b0A); MFMA16(acc[1][0], aD, b0B);
        MFMA16(acc[1][1], aC, b0C); MFMA16(acc[1][1], aD, b0D);
        __builtin_amdgcn_s_setprio(0);
        SBAR();
        bf16x8 b1A = ldB(p, 2, 0), b1B = ldB(p, 2, 1), b1C = ldB(p, 3, 0), b1D = ldB(p, 3, 1);
        if (kt + 2 < NK) stageB(kt + 2, 0);
        SBAR(); LGKM0();
        __builtin_amdgcn_s_setprio(1);
        MFMA16(acc[0][2], aA, b1A); MFMA16(acc[0][2], aB, b1B);
        MFMA16(acc[0][3], aA, b1C); MFMA16(acc[0][3], aB, b1D);
        MFMA16(acc[1][2], aC, b1A); MFMA16(acc[1][2], aD, b1B);
        MFMA16(acc[1][3], aC, b1C); MFMA16(acc[1][3], aD, b1D);
        __builtin_amdgcn_s_setprio(0);
        SBAR();
        aA = ldA(p, 2, 0); aB = ldA(p, 2, 1); aC = ldA(p, 3, 0); aD = ldA(p, 3, 1);
        if (kt + 2 < NK) stageB(kt + 2, 1);
        SBAR(); LGKM0();
        __builtin_amdgcn_s_setprio(1);
        MFMA16(acc[2][2], aA, b1A); MFMA16(acc[2][2], aB, b1B);
        MFMA16(acc[2][3], aA, b1C); MFMA16(acc[2][3], aB, b1D);
        MFMA16(acc[3][2], aC, b1A); MFMA16(acc[3][2], aD, b1B);
        MFMA16(acc[3][3], aC, b1C); MFMA16(acc[3][3], aD, b1D);
        __builtin_amdgcn_s_setprio(0);
        SBAR();
        if (kt + 2 < NK) stageA(kt + 2);
        SBAR();
        __builtin_amdgcn_s_setprio(1);
        MFMA16(acc[2][0], aA, b0A); MFMA16(acc[2][0], aB, b0B);
        MFMA16(acc[2][1], aA, b0C); MFMA16(acc[2][1], aB, b0D);
        MFMA16(acc[3][0], aC, b0A); MFMA16(acc[3][0], aD, b0B);
        MFMA16(acc[3][1], aC, b0C); MFMA16(acc[3][1], aD, b0D);
        __builtin_amdgcn_s_setprio(0);
        if (kt + 2 < NK) {
            asm volatile("s_waitcnt vmcnt(6)" ::: "memory");
        } else if (kt + 1 < NK) {
            asm volatile("s_waitcnt vmcnt(0)" ::: "memory");
        }
        SBAR();
    }

#pragma unroll
    for (int mi = 0; mi < 4; ++mi) {
        int gr0 = bm + wr * 64 + mi * 16 + (lane >> 4) * 4;
#pragma unroll
        for (int ni = 0; ni < 4; ++ni) {
            int gc = bn + wn * 64 + ni * 16 + (lane & 15);
            float bv = bias ? bias[gc] : 0.f;
#pragma unroll
            for (int j = 0; j < 4; ++j) {
                int gr = gr0 + j;
                if (gr >= M) continue;
                float v = acc[mi][ni][j] + bv;
                if (ACT) v = 0.5f * v * (1.0f + erff(v * 0.70710678118654752f));
                long ci = (long)gr * ldc + gc;
                if (OBF) {
                    ((unsigned short*)C)[ci] = f2bf(v);
                } else {
                    if (resid) v += resid[ci];
                    ((float*)C)[ci] = v;
                }
            }
        }
    }
}

// ---------------------------------------------------------------------------
// 2-phase bf16 MFMA GEMM — attention (small K, batched).
// ---------------------------------------------------------------------------
template <int BM, int BN, int ACT, int OBF>
__global__ __launch_bounds__(256) void gemm_bf16_kernel(
    const unsigned short* __restrict__ A,
    const unsigned short* __restrict__ Bt,
    const float* __restrict__ bias,
    const float* __restrict__ resid,
    void* __restrict__ C,
    int M, int N, int K, int lda, int ldb, int ldc, float scale, int zdiv,
    long a_s1, long a_s2, long b_s1, long b_s2, long c_s1, long c_s2) {
    constexpr int FM = BM / 32, FN = BN / 32;
    __shared__ unsigned short As[BM * 32];
    __shared__ unsigned short Bs[BN * 32];
    const int tid = threadIdx.x;
    const int lane = tid & 63;
    const int w = tid >> 6;
    const int wr = w >> 1, wc = w & 1;
    const int z = blockIdx.z;
    const long aoff = (long)(z / zdiv) * a_s1 + (long)(z % zdiv) * a_s2;
    const long boff = (long)(z / zdiv) * b_s1 + (long)(z % zdiv) * b_s2;
    const long coff = (long)(z / zdiv) * c_s1 + (long)(z % zdiv) * c_s2;
    const int bm = blockIdx.x * BM, bn = blockIdx.y * BN;

    const unsigned short* Ab = A + aoff + (long)bm * lda;
    const unsigned short* Bb = Bt + boff + (long)bn * ldb;

    f32x4 acc[FM][FN] = {};

    for (int k0 = 0; k0 < K; k0 += 32) {
#pragma unroll
        for (int c = tid; c < BM * 4; c += 256) {
            const unsigned short* g = Ab + (long)(c >> 2) * lda + k0 + (c & 3) * 8;
            __builtin_amdgcn_global_load_lds(
                (const __attribute__((address_space(1))) void*)g,
                (__attribute__((address_space(3))) void*)&As[c * 8], 16, 0, 0);
        }
#pragma unroll
        for (int c = tid; c < BN * 4; c += 256) {
            const unsigned short* g = Bb + (long)(c >> 2) * ldb + k0 + (c & 3) * 8;
            __builtin_amdgcn_global_load_lds(
                (const __attribute__((address_space(1))) void*)g,
                (__attribute__((address_space(3))) void*)&Bs[c * 8], 16, 0, 0);
        }
        __syncthreads();

        bf16x8 af[FM], bfr[FN];
#pragma unroll
        for (int m = 0; m < FM; ++m) {
            int rr = wr * (BM / 2) + m * 16 + (lane & 15);
            af[m] = *(const bf16x8*)&As[rr * 32 + (lane >> 4) * 8];
        }
#pragma unroll
        for (int n = 0; n < FN; ++n) {
            int cn = wc * (BN / 2) + n * 16 + (lane & 15);
            bfr[n] = *(const bf16x8*)&Bs[cn * 32 + (lane >> 4) * 8];
        }
#pragma unroll
        for (int m = 0; m < FM; ++m)
#pragma unroll
            for (int n = 0; n < FN; ++n)
                acc[m][n] = __builtin_amdgcn_mfma_f32_16x16x32_bf16(
                    af[m], bfr[n], acc[m][n], 0, 0, 0);
        __syncthreads();
    }

#pragma unroll
    for (int m = 0; m < FM; ++m) {
#pragma unroll
        for (int n = 0; n < FN; ++n) {
            int gc = bn + wc * (BN / 2) + n * 16 + (lane & 15);
            if (gc >= N) continue;
            float bv = bias ? bias[gc] : 0.f;
#pragma unroll
            for (int j = 0; j < 4; ++j) {
                int gr = bm + wr * (BM / 2) + m * 16 + (lane >> 4) * 4 + j;
                if (gr >= M) continue;
                float v = acc[m][n][j] * scale + bv;
                if (ACT == 1) v = 0.5f * v * (1.0f + erff(v * 0.70710678118654752f));
                long ci = coff + (long)gr * ldc + gc;
                if (OBF) {
                    ((unsigned short*)C)[ci] = f2bf(v);
                } else {
                    if (resid) v += resid[ci];
                    ((float*)C)[ci] = v;
                }
            }
        }
    }
}

// ---------------------------------------------------------------------------
// Row softmax, wave-per-row (4 rows per 256-block, no barriers).
// Row = 257 real cols; writes 320 (zeroes pads 257..319).
// ---------------------------------------------------------------------------
__global__ void softmax_bf16_kernel(unsigned short* __restrict__ S) {
    long r = (long)blockIdx.x * 4 + (threadIdx.x >> 6);
    long zz = r / SEQ, ii = r % SEQ;
    unsigned short* p = S + (zz * SEQP + ii) * SEQP;
    int lane = threadIdx.x & 63;
    float v0 = bf2f(p[lane]);
    float v1 = bf2f(p[lane + 64]);
    float v2 = bf2f(p[lane + 128]);
    float v3 = bf2f(p[lane + 192]);
    float v4 = (lane == 0) ? bf2f(p[256]) : -3.4e38f;
    float m = fmaxf(fmaxf(fmaxf(v0, v1), fmaxf(v2, v3)), v4);
#pragma unroll
    for (int off = 32; off; off >>= 1) m = fmaxf(m, __shfl_xor(m, off));
    float e0 = __expf(v0 - m), e1 = __expf(v1 - m);
    float e2 = __expf(v2 - m), e3 = __expf(v3 - m);
    float e4 = (lane == 0) ? __expf(v4 - m) : 0.f;
    float s = e0 + e1 + e2 + e3 + e4;
#pragma unroll
    for (int off = 32; off; off >>= 1) s += __shfl_xor(s, off);
    float inv = 1.0f / s;
    p[lane]       = f2bf(e0 * inv);
    p[lane + 64]  = f2bf(e1 * inv);
    p[lane + 128] = f2bf(e2 * inv);
    p[lane + 192] = f2bf(e3 * inv);
    p[256 + lane] = (lane == 0) ? f2bf(e4 * inv) : 0;
}

// ---------------------------------------------------------------------------
// V repack: vT[z][d][j] = V[b,j,h,d] (bf16), zero for j >= SEQ.
// ---------------------------------------------------------------------------
__global__ void v_repack_kernel(const unsigned short* __restrict__ qkv_bf,
                                unsigned short* __restrict__ vT) {
    int z = blockIdx.x;
    int b = z / HEADS, hh = z % HEADS;
    for (int idx = threadIdx.x; idx < 64 * SEQP; idx += 256) {
        int d = idx / SEQP, j = idx % SEQP;
        unsigned short v = 0;
        if (j < SEQ)
            v = qkv_bf[((long)(b * SEQ + j)) * 2304 + 1536 + hh * 64 + d];
        vT[(long)z * 64 * SEQP + idx] = v;
    }
}

// ---------------------------------------------------------------------------
// fp32 GEMM for the tiny classifier head
// ---------------------------------------------------------------------------
__global__ void gemm_f32_kernel(const float* __restrict__ A,
                                const float* __restrict__ W,
                                const float* __restrict__ bias,
                                float* __restrict__ C,
                                int M, int N, int K) {
    __shared__ float As[16][65];
    __shared__ float Bs[16][65];
    int bm = blockIdx.x * 64, bn = blockIdx.y * 64;
    int t = threadIdx.x;
    int tx = t & 15, ty = t >> 4;
    float acc[4][4] = {};
    for (int k0 = 0; k0 < K; k0 += 16) {
        {
            int ar = bm + (t >> 2);
            int ac = k0 + (t & 3) * 4;
            float4 av = make_float4(0.f, 0.f, 0.f, 0.f);
            if (ar < M) av = *(const float4*)(A + (long)ar * K + ac);
            int kk = (t & 3) * 4, rr = t >> 2;
            As[kk + 0][rr] = av.x; As[kk + 1][rr] = av.y;
            As[kk + 2][rr] = av.z; As[kk + 3][rr] = av.w;
        }
        {
            int wr2 = k0 + (t >> 4);
            int wc2 = bn + (t & 15) * 4;
            float4 wv;
            wv.x = (wc2 + 0 < N) ? W[(long)wr2 * N + wc2 + 0] : 0.f;
            wv.y = (wc2 + 1 < N) ? W[(long)wr2 * N + wc2 + 1] : 0.f;
            wv.z = (wc2 + 2 < N) ? W[(long)wr2 * N + wc2 + 2] : 0.f;
            wv.w = (wc2 + 3 < N) ? W[(long)wr2 * N + wc2 + 3] : 0.f;
            int kr = t >> 4, nc = (t & 15) * 4;
            Bs[kr][nc + 0] = wv.x; Bs[kr][nc + 1] = wv.y;
            Bs[kr][nc + 2] = wv.z; Bs[kr][nc + 3] = wv.w;
        }
        __syncthreads();
#pragma unroll
        for (int kk = 0; kk < 16; ++kk) {
            float a0 = As[kk][ty * 4 + 0], a1 = As[kk][ty * 4 + 1];
            float a2 = As[kk][ty * 4 + 2], a3 = As[kk][ty * 4 + 3];
            float b0 = Bs[kk][tx], b1 = Bs[kk][tx + 16];
            float b2 = Bs[kk][tx + 32], b3 = Bs[kk][tx + 48];
            acc[0][0] += a0 * b0; acc[0][1] += a0 * b1; acc[0][2] += a0 * b2; acc[0][3] += a0 * b3;
            acc[1][0] += a1 * b0; acc[1][1] += a1 * b1; acc[1][2] += a1 * b2; acc[1][3] += a1 * b3;
            acc[2][0] += a2 * b0; acc[2][1] += a2 * b1; acc[2][2] += a2 * b2; acc[2][3] += a2 * b3;
            acc[3][0] += a3 * b0; acc[3][1] += a3 * b1; acc[3][2] += a3 * b2; acc[3][3] += a3 * b3;
        }
        __syncthreads();
    }
#pragma unroll
    for (int i = 0; i < 4; ++i) {
        int r = bm + ty * 4 + i;
        if (r >= M) continue;
#pragma unroll
        for (int j = 0; j < 4; ++j) {
            int c = bn + tx + 16 * j;
            if (c >= N) continue;
            C[(long)r * N + c] = acc[i][j] + (bias ? bias[c] : 0.f);
        }
    }
}

// ---------------------------------------------------------------------------
// Orchestration
// ---------------------------------------------------------------------------
extern "C" void kernel_launch(void* const* d_in, const int* in_sizes, int n_in,
                              void* d_out, int out_size, void* d_ws, size_t ws_size,
                              hipStream_t stream) {
    const float* x        = (const float*)d_in[0];
    const float* conv_w   = (const float*)d_in[1];
    const float* conv_b   = (const float*)d_in[2];
    const float* pos      = (const float*)d_in[3];
    const float* cls_tok  = (const float*)d_in[4];
    const float* ln1_w    = (const float*)d_in[5];
    const float* ln1_b    = (const float*)d_in[6];
    const float* qkv_w    = (const float*)d_in[7];
    const float* out_w    = (const float*)d_in[8];
    const float* out_b    = (const float*)d_in[9];
    const float* ln2_w    = (const float*)d_in[10];
    const float* ln2_b    = (const float*)d_in[11];
    const float* mlp_w1   = (const float*)d_in[12];
    const float* mlp_b1   = (const float*)d_in[13];
    const float* mlp_w2   = (const float*)d_in[14];
    const float* mlp_b2   = (const float*)d_in[15];
    const float* cls_ln_w = (const float*)d_in[16];
    const float* cls_ln_b = (const float*)d_in[17];
    const float* head_w   = (const float*)d_in[18];
    const float* head_b   = (const float*)d_in[19];
    float* out = (float*)d_out;

    char* cur = (char*)d_ws;
    auto alloc = [&](size_t bytes) {
        void* p = cur; cur += (bytes + 255) & ~(size_t)255; return p;
    };
    float*          h      = (float*)alloc((size_t)PAD_ROWS * DIM * 4);
    unsigned short* z_bf   = (unsigned short*)alloc((size_t)PAD_A * DIM * 2);
    unsigned short* qkv_bf = (unsigned short*)alloc((size_t)PAD_ROWS * 3 * DIM * 2);
    unsigned short* o_bf   = (unsigned short*)alloc((size_t)PAD_ROWS * DIM * 2);
    unsigned short* S      = (unsigned short*)alloc((size_t)384 * SEQP * SEQP * 2);
    unsigned short* m1     = S;  // MLP hidden aliases S (52MB <= 78.6MB)
    unsigned short* vT     = (unsigned short*)alloc((size_t)384 * 64 * SEQP * 2);
    unsigned short* qkvwT  = (unsigned short*)alloc((size_t)2304 * 768 * 2);
    unsigned short* owT    = (unsigned short*)alloc((size_t)768 * 768 * 2);
    unsigned short* w1T    = (unsigned short*)alloc((size_t)3072 * 768 * 2);
    unsigned short* w2T    = (unsigned short*)alloc((size_t)768 * 3072 * 2);
    float*          clsz   = (float*)alloc((size_t)BATCH * DIM * 4);

    patch_embed_kernel<<<ROWS, 256, 0, stream>>>(x, conv_w, conv_b, pos, cls_tok, h);

    for (int l = 0; l < DEPTH; ++l) {
        transpose_bf16_kernel<<<dim3(24, 72), 256, 0, stream>>>(
            qkv_w + (long)l * DIM * 3 * DIM, qkvwT, DIM, 3 * DIM);
        transpose_bf16_kernel<<<dim3(24, 24), 256, 0, stream>>>(
            out_w + (long)l * DIM * DIM, owT, DIM, DIM);
        transpose_bf16_kernel<<<dim3(24, 96), 256, 0, stream>>>(
            mlp_w1 + (long)l * DIM * DIM_MLP, w1T, DIM, DIM_MLP);
        transpose_bf16_kernel<<<dim3(96, 24), 256, 0, stream>>>(
            mlp_w2 + (long)l * DIM_MLP * DIM, w2T, DIM_MLP, DIM);

        layernorm_kernel<1><<<ROWS, 256, 0, stream>>>(
            h, DIM, ln1_w + (long)l * DIM, ln1_b + (long)l * DIM, z_bf);

        // qkv = z @ qkv_w   [8224 x 2304], K=768  (256^2 8-phase)
        gemm256_kernel<12, 0><<<33 * 9, 512, 0, stream>>>(
            z_bf, qkvwT, nullptr, qkv_bf, ROWS, 9, DIM, DIM, 3 * DIM);

        // S = scale * Q @ K^T  per (b,h); padded 320x320, bf16 out
        gemm_bf16_kernel<64, 64, 0, 1><<<dim3(5, 5, BATCH * HEADS), 256, 0, stream>>>(
            qkv_bf, qkv_bf + 768, nullptr, nullptr, S,
            SEQP, SEQP, DIM_HEAD, 3 * DIM, 3 * DIM, SEQP, SCALE, HEADS,
            (long)SEQ * 3 * DIM, 64, (long)SEQ * 3 * DIM, 64,
            (long)HEADS * SEQP * SEQP, (long)SEQP * SEQP);

        softmax_bf16_kernel<<<(BATCH * HEADS * SEQ) / 4, 256, 0, stream>>>(S);
        v_repack_kernel<<<BATCH * HEADS, 256, 0, stream>>>(qkv_bf, vT);

        // o = softmax(S) @ V   [257 x 64] per (b,h)
        gemm_bf16_kernel<64, 64, 0, 1><<<dim3(5, 1, BATCH * HEADS), 256, 0, stream>>>(
            S, vT, nullptr, nullptr, o_bf,
            SEQ, DIM_HEAD, SEQP, SEQP, SEQP, DIM, 1.0f, HEADS,
            (long)HEADS * SEQP * SEQP, (long)SEQP * SEQP,
            (long)HEADS * 64 * SEQP, (long)64 * SEQP,
            (long)SEQ * DIM, 64);

        // h = o @ out_w + out_b + h   (fp32, in-place residual), K=768
        gemm8_kernel<12, 0, 0><<<65 * 3, 512, 0, stream>>>(
            o_bf, owT, out_b + (long)l * DIM, h, h, ROWS, 3, DIM, DIM, DIM);

        layernorm_kernel<1><<<ROWS, 256, 0, stream>>>(
            h, DIM, ln2_w + (long)l * DIM, ln2_b + (long)l * DIM, z_bf);

        // m1 = gelu(z @ w1 + b1)   [8224 x 3072], K=768  (256^2 8-phase)
        gemm256_kernel<12, 1><<<33 * 12, 512, 0, stream>>>(
            z_bf, w1T, mlp_b1 + (long)l * DIM_MLP, m1, ROWS, 12, DIM, DIM, DIM_MLP);

        // h = m1 @ w2 + b2 + h   (fp32, in-place residual), K=3072
        gemm8_kernel<48, 0, 0><<<65 * 3, 512, 0, stream>>>(
            m1, w2T, mlp_b2 + (long)l * DIM, h, h, ROWS, 3, DIM_MLP, DIM_MLP, DIM);
    }

    layernorm_kernel<0><<<BATCH, 256, 0, stream>>>(
        h, (long)SEQ * DIM, cls_ln_w, cls_ln_b, clsz);
    gemm_f32_kernel<<<dim3(1, 16), 256, 0, stream>>>(
        clsz, head_w, head_b, out, BATCH, NUM_CLASSES, DIM);
}

// Round 5
// 4625.091 us; speedup vs baseline: 6.4101x; 1.1623x over previous
//
#include <hip/hip_runtime.h>
#include <math.h>

#define DIM 768
#define DEPTH 12
#define HEADS 12
#define DIM_HEAD 64
#define DIM_MLP 3072
#define PATCH 16
#define NUM_PATCHES 256
#define SEQ 257
#define NUM_CLASSES 1000
#define BATCH 32
#define SCALE 0.125f
#define EPS 1e-5f
#define ROWS 8224         // BATCH*SEQ
#define PAD_ROWS 8320     // 65*128
#define PAD_A 8448        // 33*256

typedef short bf16x8 __attribute__((ext_vector_type(8)));
typedef float f32x4 __attribute__((ext_vector_type(4)));

__device__ inline unsigned short f2bf(float f) {
    union { float f; unsigned int u; } c; c.f = f;
    unsigned int u = c.u;
    return (unsigned short)((u + 0x7fffu + ((u >> 16) & 1u)) >> 16);
}

#define MFMA16(d, a, b) d = __builtin_amdgcn_mfma_f32_16x16x32_bf16(a, b, d, 0, 0, 0)
#define SBAR() asm volatile("s_barrier" ::: "memory")
#define LGKM0() asm volatile("s_waitcnt lgkmcnt(0)" ::: "memory")

// ---------------------------------------------------------------------------
// Patch embed (fp32)
// ---------------------------------------------------------------------------
__global__ void patch_embed_kernel(const float* __restrict__ x,
                                   const float* __restrict__ conv_w,
                                   const float* __restrict__ conv_b,
                                   const float* __restrict__ pos,
                                   const float* __restrict__ cls_tok,
                                   float* __restrict__ h) {
    int row = blockIdx.x;
    int b = row / SEQ;
    int r = row % SEQ;
    int t = threadIdx.x;
    float* out = h + (long)row * DIM;
    if (r == 0) {
        for (int d = t; d < DIM; d += 256)
            out[d] = cls_tok[d] + pos[d];
        return;
    }
    int p = r - 1;
    const float* xp = x + (long)b * 4096 + p * PATCH;
    float xv[PATCH];
#pragma unroll
    for (int k = 0; k < PATCH; ++k) xv[k] = xp[k];
    for (int d = t; d < DIM; d += 256) {
        float acc = conv_b[d];
#pragma unroll
        for (int k = 0; k < PATCH; ++k)
            acc += xv[k] * conv_w[k * DIM + d];
        out[d] = acc + pos[(long)r * DIM + d];
    }
}

// ---------------------------------------------------------------------------
// LayerNorm (fp32 in, fp32 or bf16 out)
// ---------------------------------------------------------------------------
template <int OBF>
__global__ void layernorm_kernel(const float* __restrict__ in, long in_stride,
                                 const float* __restrict__ w,
                                 const float* __restrict__ bia,
                                 void* __restrict__ out) {
    __shared__ float red[8];
    long row = blockIdx.x;
    const float* src = in + row * in_stride;
    int t = threadIdx.x;
    float v0 = src[t], v1 = src[t + 256], v2 = src[t + 512];
    float s = v0 + v1 + v2;
    float q = v0 * v0 + v1 * v1 + v2 * v2;
#pragma unroll
    for (int off = 32; off; off >>= 1) {
        s += __shfl_down(s, off);
        q += __shfl_down(q, off);
    }
    if ((t & 63) == 0) { red[t >> 6] = s; red[4 + (t >> 6)] = q; }
    __syncthreads();
    if (t == 0) {
        float ss = red[0] + red[1] + red[2] + red[3];
        float qq = red[4] + red[5] + red[6] + red[7];
        float mu = ss * (1.0f / DIM);
        float var = qq * (1.0f / DIM) - mu * mu;
        red[0] = mu;
        red[1] = rsqrtf(var + EPS);
    }
    __syncthreads();
    float mu = red[0], rstd = red[1];
    float o0 = (v0 - mu) * rstd * w[t] + bia[t];
    float o1 = (v1 - mu) * rstd * w[t + 256] + bia[t + 256];
    float o2 = (v2 - mu) * rstd * w[t + 512] + bia[t + 512];
    if (OBF) {
        unsigned short* dst = (unsigned short*)out + row * DIM;
        dst[t] = f2bf(o0); dst[t + 256] = f2bf(o1); dst[t + 512] = f2bf(o2);
    } else {
        float* dst = (float*)out + row * DIM;
        dst[t] = o0; dst[t + 256] = o1; dst[t + 512] = o2;
    }
}

// ---------------------------------------------------------------------------
// All 4 weight transposes of one layer in a single dispatch.
// out[n][k] = bf16(in[k][n]) per 32x32 tile; grid 6912 blocks.
// ---------------------------------------------------------------------------
__global__ void transpose_all_kernel(const float* __restrict__ qw,
                                     const float* __restrict__ ow,
                                     const float* __restrict__ w1,
                                     const float* __restrict__ w2,
                                     unsigned short* __restrict__ qwT,
                                     unsigned short* __restrict__ owT,
                                     unsigned short* __restrict__ w1T,
                                     unsigned short* __restrict__ w2T) {
    __shared__ float tile[32][33];
    int t = blockIdx.x;
    const float* src; unsigned short* dst; int K, N, kt, nt;
    if (t < 1728)      {            src = qw; dst = qwT; K = 768;  N = 2304; kt = t % 24; nt = t / 24; }
    else if (t < 2304) { t -= 1728; src = ow; dst = owT; K = 768;  N = 768;  kt = t % 24; nt = t / 24; }
    else if (t < 4608) { t -= 2304; src = w1; dst = w1T; K = 768;  N = 3072; kt = t % 24; nt = t / 24; }
    else               { t -= 4608; src = w2; dst = w2T; K = 3072; N = 768;  kt = t % 96; nt = t / 96; }
    int k0 = kt * 32, n0 = nt * 32;
    int c = threadIdx.x & 31, r0 = threadIdx.x >> 5;
#pragma unroll
    for (int rr = r0; rr < 32; rr += 8)
        tile[rr][c] = src[(long)(k0 + rr) * N + n0 + c];
    __syncthreads();
#pragma unroll
    for (int rr = r0; rr < 32; rr += 8)
        dst[(long)(n0 + rr) * K + k0 + c] = f2bf(tile[c][rr]);
}

// ---------------------------------------------------------------------------
// Fused attention: per (b,h,q-tile of 64 rows): S = scale*Q.K^T (MFMA),
// exact softmax over 257 cols (f32, in-register), P->LDS bf16, O = P.V (MFMA).
// KV padded to 288 (9 k-steps); cols >=257 masked -inf; V rows >=257 zeroed.
// LDS (shorts): Qs[64][64]swz @0 | Ks[288][64]swz @4096 | Vt[64][296] @22528
//               | Ps[64][296] @41472   (total 120832 B)
// ---------------------------------------------------------------------------
__global__ __launch_bounds__(256) void attn_kernel(const unsigned short* __restrict__ qkv,
                                                   unsigned short* __restrict__ o) {
    __shared__ unsigned short sh[60416];
    const int tid = threadIdx.x;
    const int lane = tid & 63;
    const int w = tid >> 6;

    // T1 bijective remap: same-(b,h) q-tiles land on the same XCD consecutively
    const int nwg = gridDim.x;                 // 1920
    const int orig = blockIdx.x;
    const int q = nwg >> 3, r = nwg & 7;
    const int xcd = orig & 7, idx = orig >> 3;
    const int wg = (xcd < r ? xcd * (q + 1) : r * (q + 1) + (xcd - r) * q) + idx;
    const int bh = wg / 5, qt = wg % 5;
    const int b = bh / HEADS, hh = bh % HEADS;
    const unsigned short* qbase = qkv + (long)b * SEQ * 2304 + hh * 64;
    const unsigned short* kbase = qbase + 768;
    const unsigned short* vbase = qbase + 1536;

    // stage Q [64][64] (XOR-swizzled, linear LDS dest)
#pragma unroll
    for (int u = 0; u < 2; ++u) {
        int c = tid + u * 256;
        int j = c >> 3, cb = c & 7;
        int gj = qt * 64 + j; if (gj > 256) gj = 256;
        const unsigned short* g = qbase + (long)gj * 2304 + ((cb ^ (j & 7)) << 3);
        __builtin_amdgcn_global_load_lds(
            (const __attribute__((address_space(1))) void*)g,
            (__attribute__((address_space(3))) void*)&sh[j * 64 + cb * 8], 16, 0, 0);
    }
    // stage K [288][64] (XOR-swizzled; rows >=257 clamped, masked later)
#pragma unroll
    for (int u = 0; u < 9; ++u) {
        int c = tid + u * 256;
        int j = c >> 3, cb = c & 7;
        int gj = j > 256 ? 256 : j;
        const unsigned short* g = kbase + (long)gj * 2304 + ((cb ^ (j & 7)) << 3);
        __builtin_amdgcn_global_load_lds(
            (const __attribute__((address_space(1))) void*)g,
            (__attribute__((address_space(3))) void*)&sh[4096 + j * 64 + cb * 8], 16, 0, 0);
    }
    // stage V transposed [64 d][296 k], rows k>=257 zeroed
#pragma unroll
    for (int u = 0; u < 9; ++u) {
        int c = tid + u * 256;
        int j = c >> 3, dc = c & 7;
        short vv[8] = {0, 0, 0, 0, 0, 0, 0, 0};
        if (j < SEQ) *(bf16x8*)vv = *(const bf16x8*)(vbase + (long)j * 2304 + dc * 8);
#pragma unroll
        for (int e = 0; e < 8; ++e)
            sh[22528 + (dc * 8 + e) * 296 + j] = (unsigned short)vv[e];
    }
    __syncthreads();

    // S = Q.K^T : per wave rows w*16..+15, 18 col-frags (288 cols)
    f32x4 s[18] = {};
#pragma unroll
    for (int ks = 0; ks < 2; ++ks) {
        int arow = w * 16 + (lane & 15);
        int cb = ks * 4 + (lane >> 4);
        bf16x8 aq = *(const bf16x8*)&sh[arow * 64 + ((cb ^ (arow & 7)) << 3)];
#pragma unroll
        for (int nf = 0; nf < 18; ++nf) {
            int brow = nf * 16 + (lane & 15);
            bf16x8 bk = *(const bf16x8*)&sh[4096 + brow * 64 + ((cb ^ (brow & 7)) << 3)];
            MFMA16(s[nf], aq, bk);
        }
    }

    // exact softmax (f32); acc layout: col = nf*16+(lane&15), row = (lane>>4)*4+j
    float inv[4];
#pragma unroll
    for (int j = 0; j < 4; ++j) {
        float m_ = -3.0e38f;
#pragma unroll
        for (int nf = 0; nf < 18; ++nf) {
            int col = nf * 16 + (lane & 15);
            float x = (col < SEQ) ? s[nf][j] * SCALE : -3.0e38f;
            s[nf][j] = x;
            m_ = fmaxf(m_, x);
        }
#pragma unroll
        for (int off = 1; off < 16; off <<= 1) m_ = fmaxf(m_, __shfl_xor(m_, off));
        float sm = 0.f;
#pragma unroll
        for (int nf = 0; nf < 18; ++nf) {
            float e = __expf(s[nf][j] - m_);
            s[nf][j] = e;
            sm += e;
        }
#pragma unroll
        for (int off = 1; off < 16; off <<= 1) sm += __shfl_xor(sm, off);
        inv[j] = 1.0f / sm;
    }
    // P -> LDS bf16
#pragma unroll
    for (int nf = 0; nf < 18; ++nf) {
        int col = nf * 16 + (lane & 15);
#pragma unroll
        for (int j = 0; j < 4; ++j) {
            int row = w * 16 + (lane >> 4) * 4 + j;
            sh[41472 + row * 296 + col] = f2bf(s[nf][j] * inv[j]);
        }
    }
    __syncthreads();

    // O = P.V : per wave rows w*16..+15 x 64 d, 9 k-steps
    f32x4 oa[4] = {};
#pragma unroll
    for (int ks = 0; ks < 9; ++ks) {
        int prow = w * 16 + (lane & 15);
        bf16x8 ap = *(const bf16x8*)&sh[41472 + prow * 296 + ks * 32 + (lane >> 4) * 8];
#pragma unroll
        for (int n = 0; n < 4; ++n) {
            int drow = n * 16 + (lane & 15);
            bf16x8 bv = *(const bf16x8*)&sh[22528 + drow * 296 + ks * 32 + (lane >> 4) * 8];
            MFMA16(oa[n], ap, bv);
        }
    }
#pragma unroll
    for (int n = 0; n < 4; ++n) {
        int col = hh * 64 + n * 16 + (lane & 15);
#pragma unroll
        for (int j = 0; j < 4; ++j) {
            int gr = qt * 64 + w * 16 + (lane >> 4) * 4 + j;
            if (gr < SEQ)
                o[((long)(b * SEQ + gr)) * DIM + col] = f2bf(oa[n][j]);
        }
    }
}

// ---------------------------------------------------------------------------
// 256x256 8-phase bf16 MFMA GEMM (m201 geometry) — qkv & mlp1.
// ---------------------------------------------------------------------------
template <int NK, int ACT>
__global__ __launch_bounds__(512, 2) void gemm256_kernel(
    const unsigned short* __restrict__ A,
    const unsigned short* __restrict__ Bt,
    const float* __restrict__ bias,
    unsigned short* __restrict__ C,
    int M, int GY, int lda, int ldb, int ldc) {
    __shared__ unsigned short sh[65536];
    const int tid = threadIdx.x;
    const int lane = tid & 63;
    const int w = tid >> 6;
    const int wr = w >> 2;
    const int wn = w & 3;

    const int nwg = gridDim.x;
    const int orig = blockIdx.x;
    const int q = nwg >> 3, r = nwg & 7;
    const int xcd = orig & 7, idx = orig >> 3;
    const int wg = (xcd < r ? xcd * (q + 1) : r * (q + 1) + (xcd - r) * q) + idx;
    const int bm = (wg / GY) * 256;
    const int bn = (wg % GY) * 256;

    const unsigned short* Ag = A + (long)bm * lda;
    const unsigned short* Bg = Bt + (long)bn * ldb;

    auto stageA = [&](int kt, int half) {
        unsigned short* Lb = &sh[(kt & 1) * 32768];
#pragma unroll
        for (int u = 0; u < 2; ++u) {
            int c = tid + u * 512;
            int lr = c >> 3, cb = c & 7;
            int row = ((lr >> 6) << 7) + (half << 6) + (lr & 63);
            const unsigned short* g = Ag + (long)row * lda + kt * 64 + ((cb ^ (row & 7)) << 3);
            __builtin_amdgcn_global_load_lds(
                (const __attribute__((address_space(1))) void*)g,
                (__attribute__((address_space(3))) void*)&Lb[row * 64 + (cb << 3)], 16, 0, 0);
        }
    };
    auto stageB = [&](int kt, int half) {
        unsigned short* Lb = &sh[(kt & 1) * 32768 + 16384];
#pragma unroll
        for (int u = 0; u < 2; ++u) {
            int c = tid + u * 512;
            int lr = c >> 3, cb = c & 7;
            int row = ((lr >> 5) << 6) + (half << 5) + (lr & 31);
            const unsigned short* g = Bg + (long)row * ldb + kt * 64 + ((cb ^ (row & 7)) << 3);
            __builtin_amdgcn_global_load_lds(
                (const __attribute__((address_space(1))) void*)g,
                (__attribute__((address_space(3))) void*)&Lb[row * 64 + (cb << 3)], 16, 0, 0);
        }
    };
    auto ldA = [&](int p, int m, int ks) {
        int row = wr * 128 + m * 16 + (lane & 15);
        int cb = ks * 4 + (lane >> 4);
        return *(const bf16x8*)&sh[p * 32768 + row * 64 + ((cb ^ (row & 7)) << 3)];
    };
    auto ldB = [&](int p, int n, int ks) {
        int row = wn * 64 + n * 16 + (lane & 15);
        int cb = ks * 4 + (lane >> 4);
        return *(const bf16x8*)&sh[p * 32768 + 16384 + row * 64 + ((cb ^ (row & 7)) << 3)];
    };

    f32x4 acc[8][4] = {};

    stageA(0, 0); stageA(0, 1); stageB(0, 0); stageB(0, 1);
    stageA(1, 0); stageA(1, 1); stageB(1, 0); stageB(1, 1);
    asm volatile("s_waitcnt vmcnt(8)" ::: "memory");
    SBAR();

    bf16x8 a[4][2], b01[2][2], b23[2][2];
    for (int kt = 0; kt < NK; ++kt) {
        const int p = kt & 1;
#pragma unroll
        for (int m = 0; m < 4; ++m) { a[m][0] = ldA(p, m, 0); a[m][1] = ldA(p, m, 1); }
#pragma unroll
        for (int n = 0; n < 2; ++n) { b01[n][0] = ldB(p, n, 0); b01[n][1] = ldB(p, n, 1); }
        SBAR(); LGKM0();
        __builtin_amdgcn_s_setprio(1);
#pragma unroll
        for (int m = 0; m < 4; ++m)
#pragma unroll
            for (int n = 0; n < 2; ++n) {
                MFMA16(acc[m][n], a[m][0], b01[n][0]);
                MFMA16(acc[m][n], a[m][1], b01[n][1]);
            }
        __builtin_amdgcn_s_setprio(0);
        SBAR();
#pragma unroll
        for (int n = 0; n < 2; ++n) { b23[n][0] = ldB(p, n + 2, 0); b23[n][1] = ldB(p, n + 2, 1); }
        if (kt + 2 < NK) stageA(kt + 2, 0);
        SBAR(); LGKM0();
        __builtin_amdgcn_s_setprio(1);
#pragma unroll
        for (int m = 0; m < 4; ++m)
#pragma unroll
            for (int n = 0; n < 2; ++n) {
                MFMA16(acc[m][n + 2], a[m][0], b23[n][0]);
                MFMA16(acc[m][n + 2], a[m][1], b23[n][1]);
            }
        __builtin_amdgcn_s_setprio(0);
        SBAR();
#pragma unroll
        for (int m = 0; m < 4; ++m) { a[m][0] = ldA(p, m + 4, 0); a[m][1] = ldA(p, m + 4, 1); }
        if (kt + 2 < NK) stageB(kt + 2, 0);
        SBAR(); LGKM0();
        __builtin_amdgcn_s_setprio(1);
#pragma unroll
        for (int m = 0; m < 4; ++m)
#pragma unroll
            for (int n = 0; n < 2; ++n) {
                MFMA16(acc[m + 4][n + 2], a[m][0], b23[n][0]);
                MFMA16(acc[m + 4][n + 2], a[m][1], b23[n][1]);
            }
        __builtin_amdgcn_s_setprio(0);
        SBAR();
        if (kt + 2 < NK) { stageA(kt + 2, 1); stageB(kt + 2, 1); }
        SBAR();
        __builtin_amdgcn_s_setprio(1);
#pragma unroll
        for (int m = 0; m < 4; ++m)
#pragma unroll
            for (int n = 0; n < 2; ++n) {
                MFMA16(acc[m + 4][n], a[m][0], b01[n][0]);
                MFMA16(acc[m + 4][n], a[m][1], b01[n][1]);
            }
        __builtin_amdgcn_s_setprio(0);
        if (kt + 2 < NK) {
            asm volatile("s_waitcnt vmcnt(8)" ::: "memory");
        } else if (kt + 1 < NK) {
            asm volatile("s_waitcnt vmcnt(0)" ::: "memory");
        }
        SBAR();
    }

#pragma unroll
    for (int mi = 0; mi < 8; ++mi) {
        int gr0 = bm + wr * 128 + mi * 16 + (lane >> 4) * 4;
#pragma unroll
        for (int ni = 0; ni < 4; ++ni) {
            int gc = bn + wn * 64 + ni * 16 + (lane & 15);
            float bv = bias ? bias[gc] : 0.f;
#pragma unroll
            for (int j = 0; j < 4; ++j) {
                int gr = gr0 + j;
                if (gr >= M) continue;
                float v = acc[mi][ni][j] + bv;
                if (ACT) v = 0.5f * v * (1.0f + erff(v * 0.70710678118654752f));
                C[(long)gr * ldc + gc] = f2bf(v);
            }
        }
    }
}

// ---------------------------------------------------------------------------
// 8-phase 128x256 bf16 MFMA GEMM — proj & mlp2 (N=768, fp32 resid out).
// ---------------------------------------------------------------------------
template <int NK, int ACT, int OBF>
__global__ __launch_bounds__(512, 2) void gemm8_kernel(
    const unsigned short* __restrict__ A,
    const unsigned short* __restrict__ Bt,
    const float* __restrict__ bias,
    const float* __restrict__ resid,
    void* __restrict__ C,
    int M, int GY, int lda, int ldb, int ldc) {
    __shared__ unsigned short sh[49152];
    const int tid = threadIdx.x;
    const int lane = tid & 63;
    const int w = tid >> 6;
    const int wr = w >> 2;
    const int wn = w & 3;

    const int nwg = gridDim.x;
    const int orig = blockIdx.x;
    const int q = nwg >> 3, r = nwg & 7;
    const int xcd = orig & 7, idx = orig >> 3;
    const int wg = (xcd < r ? xcd * (q + 1) : r * (q + 1) + (xcd - r) * q) + idx;
    const int bm = (wg / GY) * 128;
    const int bn = (wg % GY) * 256;

    const unsigned short* Ag = A + (long)bm * lda;
    const unsigned short* Bg = Bt + (long)bn * ldb;

    auto stageA = [&](int kt) {
        unsigned short* Lb = &sh[(kt & 1) * 24576];
#pragma unroll
        for (int u = 0; u < 2; ++u) {
            int c = tid + u * 512;
            int lr = c >> 3, cb = c & 7;
            const unsigned short* g = Ag + (long)lr * lda + kt * 64 + ((cb ^ (lr & 7)) << 3);
            __builtin_amdgcn_global_load_lds(
                (const __attribute__((address_space(1))) void*)g,
                (__attribute__((address_space(3))) void*)&Lb[lr * 64 + (cb << 3)], 16, 0, 0);
        }
    };
    auto stageB = [&](int kt, int half) {
        unsigned short* Lb = &sh[(kt & 1) * 24576 + 8192];
#pragma unroll
        for (int u = 0; u < 2; ++u) {
            int c = tid + u * 512;
            int lr = c >> 3, cb = c & 7;
            int br = ((lr >> 5) << 6) + (half << 5) + (lr & 31);
            const unsigned short* g = Bg + (long)br * ldb + kt * 64 + ((cb ^ (br & 7)) << 3);
            __builtin_amdgcn_global_load_lds(
                (const __attribute__((address_space(1))) void*)g,
                (__attribute__((address_space(3))) void*)&Lb[br * 64 + (cb << 3)], 16, 0, 0);
        }
    };
    auto ldA = [&](int p, int ms, int ks) {
        int row = wr * 64 + ms * 16 + (lane & 15);
        int cb = ks * 4 + (lane >> 4);
        return *(const bf16x8*)&sh[p * 24576 + row * 64 + ((cb ^ (row & 7)) << 3)];
    };
    auto ldB = [&](int p, int ns, int ks) {
        int br = wn * 64 + ns * 16 + (lane & 15);
        int cb = ks * 4 + (lane >> 4);
        return *(const bf16x8*)&sh[p * 24576 + 8192 + br * 64 + ((cb ^ (br & 7)) << 3)];
    };

    f32x4 acc[4][4] = {};

    stageB(0, 0); stageB(0, 1); stageA(0);
    stageB(1, 0); stageB(1, 1); stageA(1);
    asm volatile("s_waitcnt vmcnt(6)" ::: "memory");
    SBAR();

#pragma unroll 2
    for (int kt = 0; kt < NK; ++kt) {
        const int p = kt & 1;
        bf16x8 aA = ldA(p, 0, 0), aB = ldA(p, 0, 1), aC = ldA(p, 1, 0), aD = ldA(p, 1, 1);
        bf16x8 b0A = ldB(p, 0, 0), b0B = ldB(p, 0, 1), b0C = ldB(p, 1, 0), b0D = ldB(p, 1, 1);
        SBAR(); LGKM0();
        __builtin_amdgcn_s_setprio(1);
        MFMA16(acc[0][0], aA, b0A); MFMA16(acc[0][0], aB, b0B);
        MFMA16(acc[0][1], aA, b0C); MFMA16(acc[0][1], aB, b0D);
        MFMA16(acc[1][0], aC, b0A); MFMA16(acc[1][0], aD, b0B);
        MFMA16(acc[1][1], aC, b0C); MFMA16(acc[1][1], aD, b0D);
        __builtin_amdgcn_s_setprio(0);
        SBAR();
        bf16x8 b1A = ldB(p, 2, 0), b1B = ldB(p, 2, 1), b1C = ldB(p, 3, 0), b1D = ldB(p, 3, 1);
        if (kt + 2 < NK) stageB(kt + 2, 0);
        SBAR(); LGKM0();
        __builtin_amdgcn_s_setprio(1);
        MFMA16(acc[0][2], aA, b1A); MFMA16(acc[0][2], aB, b1B);
        MFMA16(acc[0][3], aA, b1C); MFMA16(acc[0][3], aB, b1D);
        MFMA16(acc[1][2], aC, b1A); MFMA16(acc[1][2], aD, b1B);
        MFMA16(acc[1][3], aC, b1C); MFMA16(acc[1][3], aD, b1D);
        __builtin_amdgcn_s_setprio(0);
        SBAR();
        aA = ldA(p, 2, 0); aB = ldA(p, 2, 1); aC = ldA(p, 3, 0); aD = ldA(p, 3, 1);
        if (kt + 2 < NK) stageB(kt + 2, 1);
        SBAR(); LGKM0();
        __builtin_amdgcn_s_setprio(1);
        MFMA16(acc[2][2], aA, b1A); MFMA16(acc[2][2], aB, b1B);
        MFMA16(acc[2][3], aA, b1C); MFMA16(acc[2][3], aB, b1D);
        MFMA16(acc[3][2], aC, b1A); MFMA16(acc[3][2], aD, b1B);
        MFMA16(acc[3][3], aC, b1C); MFMA16(acc[3][3], aD, b1D);
        __builtin_amdgcn_s_setprio(0);
        SBAR();
        if (kt + 2 < NK) stageA(kt + 2);
        SBAR();
        __builtin_amdgcn_s_setprio(1);
        MFMA16(acc[2][0], aA, b0A); MFMA16(acc[2][0], aB, b0B);
        MFMA16(acc[2][1], aA, b0C); MFMA16(acc[2][1], aB, b0D);
        MFMA16(acc[3][0], aC, b0A); MFMA16(acc[3][0], aD, b0B);
        MFMA16(acc[3][1], aC, b0C); MFMA16(acc[3][1], aD, b0D);
        __builtin_amdgcn_s_setprio(0);
        if (kt + 2 < NK) {
            asm volatile("s_waitcnt vmcnt(6)" ::: "memory");
        } else if (kt + 1 < NK) {
            asm volatile("s_waitcnt vmcnt(0)" ::: "memory");
        }
        SBAR();
    }

#pragma unroll
    for (int mi = 0; mi < 4; ++mi) {
        int gr0 = bm + wr * 64 + mi * 16 + (lane >> 4) * 4;
#pragma unroll
        for (int ni = 0; ni < 4; ++ni) {
            int gc = bn + wn * 64 + ni * 16 + (lane & 15);
            float bv = bias ? bias[gc] : 0.f;
#pragma unroll
            for (int j = 0; j < 4; ++j) {
                int gr = gr0 + j;
                if (gr >= M) continue;
                float v = acc[mi][ni][j] + bv;
                if (ACT) v = 0.5f * v * (1.0f + erff(v * 0.70710678118654752f));
                long ci = (long)gr * ldc + gc;
                if (OBF) {
                    ((unsigned short*)C)[ci] = f2bf(v);
                } else {
                    if (resid) v += resid[ci];
                    ((float*)C)[ci] = v;
                }
            }
        }
    }
}

// ---------------------------------------------------------------------------
// fp32 GEMM for the tiny classifier head
// ---------------------------------------------------------------------------
__global__ void gemm_f32_kernel(const float* __restrict__ A,
                                const float* __restrict__ W,
                                const float* __restrict__ bias,
                                float* __restrict__ C,
                                int M, int N, int K) {
    __shared__ float As[16][65];
    __shared__ float Bs[16][65];
    int bm = blockIdx.x * 64, bn = blockIdx.y * 64;
    int t = threadIdx.x;
    int tx = t & 15, ty = t >> 4;
    float acc[4][4] = {};
    for (int k0 = 0; k0 < K; k0 += 16) {
        {
            int ar = bm + (t >> 2);
            int ac = k0 + (t & 3) * 4;
            float4 av = make_float4(0.f, 0.f, 0.f, 0.f);
            if (ar < M) av = *(const float4*)(A + (long)ar * K + ac);
            int kk = (t & 3) * 4, rr = t >> 2;
            As[kk + 0][rr] = av.x; As[kk + 1][rr] = av.y;
            As[kk + 2][rr] = av.z; As[kk + 3][rr] = av.w;
        }
        {
            int wr2 = k0 + (t >> 4);
            int wc2 = bn + (t & 15) * 4;
            float4 wv;
            wv.x = (wc2 + 0 < N) ? W[(long)wr2 * N + wc2 + 0] : 0.f;
            wv.y = (wc2 + 1 < N) ? W[(long)wr2 * N + wc2 + 1] : 0.f;
            wv.z = (wc2 + 2 < N) ? W[(long)wr2 * N + wc2 + 2] : 0.f;
            wv.w = (wc2 + 3 < N) ? W[(long)wr2 * N + wc2 + 3] : 0.f;
            int kr = t >> 4, nc = (t & 15) * 4;
            Bs[kr][nc + 0] = wv.x; Bs[kr][nc + 1] = wv.y;
            Bs[kr][nc + 2] = wv.z; Bs[kr][nc + 3] = wv.w;
        }
        __syncthreads();
#pragma unroll
        for (int kk = 0; kk < 16; ++kk) {
            float a0 = As[kk][ty * 4 + 0], a1 = As[kk][ty * 4 + 1];
            float a2 = As[kk][ty * 4 + 2], a3 = As[kk][ty * 4 + 3];
            float b0 = Bs[kk][tx], b1 = Bs[kk][tx + 16];
            float b2 = Bs[kk][tx + 32], b3 = Bs[kk][tx + 48];
            acc[0][0] += a0 * b0; acc[0][1] += a0 * b1; acc[0][2] += a0 * b2; acc[0][3] += a0 * b3;
            acc[1][0] += a1 * b0; acc[1][1] += a1 * b1; acc[1][2] += a1 * b2; acc[1][3] += a1 * b3;
            acc[2][0] += a2 * b0; acc[2][1] += a2 * b1; acc[2][2] += a2 * b2; acc[2][3] += a2 * b3;
            acc[3][0] += a3 * b0; acc[3][1] += a3 * b1; acc[3][2] += a3 * b2; acc[3][3] += a3 * b3;
        }
        __syncthreads();
    }
#pragma unroll
    for (int i = 0; i < 4; ++i) {
        int r = bm + ty * 4 + i;
        if (r >= M) continue;
#pragma unroll
        for (int j = 0; j < 4; ++j) {
            int c = bn + tx + 16 * j;
            if (c >= N) continue;
            C[(long)r * N + c] = acc[i][j] + (bias ? bias[c] : 0.f);
        }
    }
}

// ---------------------------------------------------------------------------
// Orchestration
// ---------------------------------------------------------------------------
extern "C" void kernel_launch(void* const* d_in, const int* in_sizes, int n_in,
                              void* d_out, int out_size, void* d_ws, size_t ws_size,
                              hipStream_t stream) {
    const float* x        = (const float*)d_in[0];
    const float* conv_w   = (const float*)d_in[1];
    const float* conv_b   = (const float*)d_in[2];
    const float* pos      = (const float*)d_in[3];
    const float* cls_tok  = (const float*)d_in[4];
    const float* ln1_w    = (const float*)d_in[5];
    const float* ln1_b    = (const float*)d_in[6];
    const float* qkv_w    = (const float*)d_in[7];
    const float* out_w    = (const float*)d_in[8];
    const float* out_b    = (const float*)d_in[9];
    const float* ln2_w    = (const float*)d_in[10];
    const float* ln2_b    = (const float*)d_in[11];
    const float* mlp_w1   = (const float*)d_in[12];
    const float* mlp_b1   = (const float*)d_in[13];
    const float* mlp_w2   = (const float*)d_in[14];
    const float* mlp_b2   = (const float*)d_in[15];
    const float* cls_ln_w = (const float*)d_in[16];
    const float* cls_ln_b = (const float*)d_in[17];
    const float* head_w   = (const float*)d_in[18];
    const float* head_b   = (const float*)d_in[19];
    float* out = (float*)d_out;

    char* cur = (char*)d_ws;
    auto alloc = [&](size_t bytes) {
        void* p = cur; cur += (bytes + 255) & ~(size_t)255; return p;
    };
    float*          h      = (float*)alloc((size_t)PAD_ROWS * DIM * 4);
    unsigned short* z_bf   = (unsigned short*)alloc((size_t)PAD_A * DIM * 2);
    unsigned short* qkv_bf = (unsigned short*)alloc((size_t)ROWS * 3 * DIM * 2);
    unsigned short* o_bf   = (unsigned short*)alloc((size_t)PAD_ROWS * DIM * 2);
    unsigned short* m1     = (unsigned short*)alloc((size_t)PAD_ROWS * DIM_MLP * 2);
    unsigned short* qkvwT  = (unsigned short*)alloc((size_t)2304 * 768 * 2);
    unsigned short* owT    = (unsigned short*)alloc((size_t)768 * 768 * 2);
    unsigned short* w1T    = (unsigned short*)alloc((size_t)3072 * 768 * 2);
    unsigned short* w2T    = (unsigned short*)alloc((size_t)768 * 3072 * 2);
    float*          clsz   = (float*)alloc((size_t)BATCH * DIM * 4);

    patch_embed_kernel<<<ROWS, 256, 0, stream>>>(x, conv_w, conv_b, pos, cls_tok, h);

    for (int l = 0; l < DEPTH; ++l) {
        transpose_all_kernel<<<6912, 256, 0, stream>>>(
            qkv_w + (long)l * DIM * 3 * DIM, out_w + (long)l * DIM * DIM,
            mlp_w1 + (long)l * DIM * DIM_MLP, mlp_w2 + (long)l * DIM_MLP * DIM,
            qkvwT, owT, w1T, w2T);

        layernorm_kernel<1><<<ROWS, 256, 0, stream>>>(
            h, DIM, ln1_w + (long)l * DIM, ln1_b + (long)l * DIM, z_bf);

        // qkv = z @ qkv_w   [8224 x 2304], K=768
        gemm256_kernel<12, 0><<<33 * 9, 512, 0, stream>>>(
            z_bf, qkvwT, nullptr, qkv_bf, ROWS, 9, DIM, DIM, 3 * DIM);

        // fused attention -> o_bf
        attn_kernel<<<384 * 5, 256, 0, stream>>>(qkv_bf, o_bf);

        // h = o @ out_w + out_b + h   (fp32, in-place residual), K=768
        gemm8_kernel<12, 0, 0><<<65 * 3, 512, 0, stream>>>(
            o_bf, owT, out_b + (long)l * DIM, h, h, ROWS, 3, DIM, DIM, DIM);

        layernorm_kernel<1><<<ROWS, 256, 0, stream>>>(
            h, DIM, ln2_w + (long)l * DIM, ln2_b + (long)l * DIM, z_bf);

        // m1 = gelu(z @ w1 + b1)   [8224 x 3072], K=768
        gemm256_kernel<12, 1><<<33 * 12, 512, 0, stream>>>(
            z_bf, w1T, mlp_b1 + (long)l * DIM_MLP, m1, ROWS, 12, DIM, DIM, DIM_MLP);

        // h = m1 @ w2 + b2 + h   (fp32, in-place residual), K=3072
        gemm8_kernel<48, 0, 0><<<65 * 3, 512, 0, stream>>>(
            m1, w2T, mlp_b2 + (long)l * DIM, h, h, ROWS, 3, DIM_MLP, DIM_MLP, DIM);
    }

    layernorm_kernel<0><<<BATCH, 256, 0, stream>>>(
        h, (long)SEQ * DIM, cls_ln_w, cls_ln_b, clsz);
    gemm_f32_kernel<<<dim3(1, 16), 256, 0, stream>>>(
        clsz, head_w, head_b, out, BATCH, NUM_CLASSES, DIM);
}

// Round 6
// 4403.716 us; speedup vs baseline: 6.7323x; 1.0503x over previous
//
#include <hip/hip_runtime.h>
#include <math.h>

#define DIM 768
#define DEPTH 12
#define HEADS 12
#define DIM_HEAD 64
#define DIM_MLP 3072
#define PATCH 16
#define NUM_PATCHES 256
#define SEQ 257
#define NUM_CLASSES 1000
#define BATCH 32
#define SCALE 0.125f
#define EPS 1e-5f
#define ROWS 8224         // BATCH*SEQ
#define PAD_ROWS 8320     // 65*128
#define PAD_A 8448

typedef short bf16x8 __attribute__((ext_vector_type(8)));
typedef float f32x4 __attribute__((ext_vector_type(4)));

__device__ inline unsigned short f2bf(float f) {
    union { float f; unsigned int u; } c; c.f = f;
    unsigned int u = c.u;
    return (unsigned short)((u + 0x7fffu + ((u >> 16) & 1u)) >> 16);
}

#define MFMA16(d, a, b) d = __builtin_amdgcn_mfma_f32_16x16x32_bf16(a, b, d, 0, 0, 0)
#define SBAR() asm volatile("s_barrier" ::: "memory")
#define LGKM0() asm volatile("s_waitcnt lgkmcnt(0)" ::: "memory")

// ---------------------------------------------------------------------------
// Patch embed (fp32)
// ---------------------------------------------------------------------------
__global__ void patch_embed_kernel(const float* __restrict__ x,
                                   const float* __restrict__ conv_w,
                                   const float* __restrict__ conv_b,
                                   const float* __restrict__ pos,
                                   const float* __restrict__ cls_tok,
                                   float* __restrict__ h) {
    int row = blockIdx.x;
    int b = row / SEQ;
    int r = row % SEQ;
    int t = threadIdx.x;
    float* out = h + (long)row * DIM;
    if (r == 0) {
        for (int d = t; d < DIM; d += 256)
            out[d] = cls_tok[d] + pos[d];
        return;
    }
    int p = r - 1;
    const float* xp = x + (long)b * 4096 + p * PATCH;
    float xv[PATCH];
#pragma unroll
    for (int k = 0; k < PATCH; ++k) xv[k] = xp[k];
    for (int d = t; d < DIM; d += 256) {
        float acc = conv_b[d];
#pragma unroll
        for (int k = 0; k < PATCH; ++k)
            acc += xv[k] * conv_w[k * DIM + d];
        out[d] = acc + pos[(long)r * DIM + d];
    }
}

// ---------------------------------------------------------------------------
// LayerNorm (fp32 in, fp32 or bf16 out)
// ---------------------------------------------------------------------------
template <int OBF>
__global__ void layernorm_kernel(const float* __restrict__ in, long in_stride,
                                 const float* __restrict__ w,
                                 const float* __restrict__ bia,
                                 void* __restrict__ out) {
    __shared__ float red[8];
    long row = blockIdx.x;
    const float* src = in + row * in_stride;
    int t = threadIdx.x;
    float v0 = src[t], v1 = src[t + 256], v2 = src[t + 512];
    float s = v0 + v1 + v2;
    float q = v0 * v0 + v1 * v1 + v2 * v2;
#pragma unroll
    for (int off = 32; off; off >>= 1) {
        s += __shfl_down(s, off);
        q += __shfl_down(q, off);
    }
    if ((t & 63) == 0) { red[t >> 6] = s; red[4 + (t >> 6)] = q; }
    __syncthreads();
    if (t == 0) {
        float ss = red[0] + red[1] + red[2] + red[3];
        float qq = red[4] + red[5] + red[6] + red[7];
        float mu = ss * (1.0f / DIM);
        float var = qq * (1.0f / DIM) - mu * mu;
        red[0] = mu;
        red[1] = rsqrtf(var + EPS);
    }
    __syncthreads();
    float mu = red[0], rstd = red[1];
    float o0 = (v0 - mu) * rstd * w[t] + bia[t];
    float o1 = (v1 - mu) * rstd * w[t + 256] + bia[t + 256];
    float o2 = (v2 - mu) * rstd * w[t + 512] + bia[t + 512];
    if (OBF) {
        unsigned short* dst = (unsigned short*)out + row * DIM;
        dst[t] = f2bf(o0); dst[t + 256] = f2bf(o1); dst[t + 512] = f2bf(o2);
    } else {
        float* dst = (float*)out + row * DIM;
        dst[t] = o0; dst[t + 256] = o1; dst[t + 512] = o2;
    }
}

// ---------------------------------------------------------------------------
// All 4 weight transposes of one layer in a single dispatch.
// ---------------------------------------------------------------------------
__global__ void transpose_all_kernel(const float* __restrict__ qw,
                                     const float* __restrict__ ow,
                                     const float* __restrict__ w1,
                                     const float* __restrict__ w2,
                                     unsigned short* __restrict__ qwT,
                                     unsigned short* __restrict__ owT,
                                     unsigned short* __restrict__ w1T,
                                     unsigned short* __restrict__ w2T) {
    __shared__ float tile[32][33];
    int t = blockIdx.x;
    const float* src; unsigned short* dst; int K, N, kt, nt;
    if (t < 1728)      {            src = qw; dst = qwT; K = 768;  N = 2304; kt = t % 24; nt = t / 24; }
    else if (t < 2304) { t -= 1728; src = ow; dst = owT; K = 768;  N = 768;  kt = t % 24; nt = t / 24; }
    else if (t < 4608) { t -= 2304; src = w1; dst = w1T; K = 768;  N = 3072; kt = t % 24; nt = t / 24; }
    else               { t -= 4608; src = w2; dst = w2T; K = 3072; N = 768;  kt = t % 96; nt = t / 96; }
    int k0 = kt * 32, n0 = nt * 32;
    int c = threadIdx.x & 31, r0 = threadIdx.x >> 5;
#pragma unroll
    for (int rr = r0; rr < 32; rr += 8)
        tile[rr][c] = src[(long)(k0 + rr) * N + n0 + c];
    __syncthreads();
#pragma unroll
    for (int rr = r0; rr < 32; rr += 8)
        dst[(long)(n0 + rr) * K + k0 + c] = f2bf(tile[c][rr]);
}

// ---------------------------------------------------------------------------
// Fused attention (round-4, proven).
// ---------------------------------------------------------------------------
__global__ __launch_bounds__(256) void attn_kernel(const unsigned short* __restrict__ qkv,
                                                   unsigned short* __restrict__ o) {
    __shared__ unsigned short sh[60416];
    const int tid = threadIdx.x;
    const int lane = tid & 63;
    const int w = tid >> 6;

    const int nwg = gridDim.x;
    const int orig = blockIdx.x;
    const int q = nwg >> 3, r = nwg & 7;
    const int xcd = orig & 7, idx = orig >> 3;
    const int wg = (xcd < r ? xcd * (q + 1) : r * (q + 1) + (xcd - r) * q) + idx;
    const int bh = wg / 5, qt = wg % 5;
    const int b = bh / HEADS, hh = bh % HEADS;
    const unsigned short* qbase = qkv + (long)b * SEQ * 2304 + hh * 64;
    const unsigned short* kbase = qbase + 768;
    const unsigned short* vbase = qbase + 1536;

#pragma unroll
    for (int u = 0; u < 2; ++u) {
        int c = tid + u * 256;
        int j = c >> 3, cb = c & 7;
        int gj = qt * 64 + j; if (gj > 256) gj = 256;
        const unsigned short* g = qbase + (long)gj * 2304 + ((cb ^ (j & 7)) << 3);
        __builtin_amdgcn_global_load_lds(
            (const __attribute__((address_space(1))) void*)g,
            (__attribute__((address_space(3))) void*)&sh[j * 64 + cb * 8], 16, 0, 0);
    }
#pragma unroll
    for (int u = 0; u < 9; ++u) {
        int c = tid + u * 256;
        int j = c >> 3, cb = c & 7;
        int gj = j > 256 ? 256 : j;
        const unsigned short* g = kbase + (long)gj * 2304 + ((cb ^ (j & 7)) << 3);
        __builtin_amdgcn_global_load_lds(
            (const __attribute__((address_space(1))) void*)g,
            (__attribute__((address_space(3))) void*)&sh[4096 + j * 64 + cb * 8], 16, 0, 0);
    }
#pragma unroll
    for (int u = 0; u < 9; ++u) {
        int c = tid + u * 256;
        int j = c >> 3, dc = c & 7;
        short vv[8] = {0, 0, 0, 0, 0, 0, 0, 0};
        if (j < SEQ) *(bf16x8*)vv = *(const bf16x8*)(vbase + (long)j * 2304 + dc * 8);
#pragma unroll
        for (int e = 0; e < 8; ++e)
            sh[22528 + (dc * 8 + e) * 296 + j] = (unsigned short)vv[e];
    }
    __syncthreads();

    f32x4 s[18] = {};
#pragma unroll
    for (int ks = 0; ks < 2; ++ks) {
        int arow = w * 16 + (lane & 15);
        int cb = ks * 4 + (lane >> 4);
        bf16x8 aq = *(const bf16x8*)&sh[arow * 64 + ((cb ^ (arow & 7)) << 3)];
#pragma unroll
        for (int nf = 0; nf < 18; ++nf) {
            int brow = nf * 16 + (lane & 15);
            bf16x8 bk = *(const bf16x8*)&sh[4096 + brow * 64 + ((cb ^ (brow & 7)) << 3)];
            MFMA16(s[nf], aq, bk);
        }
    }

    float inv[4];
#pragma unroll
    for (int j = 0; j < 4; ++j) {
        float m_ = -3.0e38f;
#pragma unroll
        for (int nf = 0; nf < 18; ++nf) {
            int col = nf * 16 + (lane & 15);
            float x = (col < SEQ) ? s[nf][j] * SCALE : -3.0e38f;
            s[nf][j] = x;
            m_ = fmaxf(m_, x);
        }
#pragma unroll
        for (int off = 1; off < 16; off <<= 1) m_ = fmaxf(m_, __shfl_xor(m_, off));
        float sm = 0.f;
#pragma unroll
        for (int nf = 0; nf < 18; ++nf) {
            float e = __expf(s[nf][j] - m_);
            s[nf][j] = e;
            sm += e;
        }
#pragma unroll
        for (int off = 1; off < 16; off <<= 1) sm += __shfl_xor(sm, off);
        inv[j] = 1.0f / sm;
    }
#pragma unroll
    for (int nf = 0; nf < 18; ++nf) {
        int col = nf * 16 + (lane & 15);
#pragma unroll
        for (int j = 0; j < 4; ++j) {
            int row = w * 16 + (lane >> 4) * 4 + j;
            sh[41472 + row * 296 + col] = f2bf(s[nf][j] * inv[j]);
        }
    }
    __syncthreads();

    f32x4 oa[4] = {};
#pragma unroll
    for (int ks = 0; ks < 9; ++ks) {
        int prow = w * 16 + (lane & 15);
        bf16x8 ap = *(const bf16x8*)&sh[41472 + prow * 296 + ks * 32 + (lane >> 4) * 8];
#pragma unroll
        for (int n = 0; n < 4; ++n) {
            int drow = n * 16 + (lane & 15);
            bf16x8 bv = *(const bf16x8*)&sh[22528 + drow * 296 + ks * 32 + (lane >> 4) * 8];
            MFMA16(oa[n], ap, bv);
        }
    }
#pragma unroll
    for (int n = 0; n < 4; ++n) {
        int col = hh * 64 + n * 16 + (lane & 15);
#pragma unroll
        for (int j = 0; j < 4; ++j) {
            int gr = qt * 64 + w * 16 + (lane >> 4) * 4 + j;
            if (gr < SEQ)
                o[((long)(b * SEQ + gr)) * DIM + col] = f2bf(oa[n][j]);
        }
    }
}

// ---------------------------------------------------------------------------
// 128x128 / BK=64 / double-buffered 64KB LDS / 2 blocks/CU / 2 barriers per
// K-step bf16 MFMA GEMM.  4 waves (2Mx2N), per-wave 64x64, 32 MFMA/K-step.
// C[M x GY*128] = act(A[M][lda] @ Bt[GY*128][ldb]^T + bias) (+resid fp32).
// A rows [bm,bm+128) staged unconditionally (padded buffers).
// Pipeline: 3 K-tiles in flight, counted vmcnt(8), never 0 in steady state.
// ---------------------------------------------------------------------------
template <int NK, int ACT, int OBF>
__global__ __launch_bounds__(256, 2) void gemmd_kernel(
    const unsigned short* __restrict__ A,
    const unsigned short* __restrict__ Bt,
    const float* __restrict__ bias,
    const float* __restrict__ resid,
    void* __restrict__ C,
    int M, int GY, int lda, int ldb, int ldc) {
    __shared__ unsigned short sh[32768];   // 2 x (128*64 A + 128*64 B)
    const int tid = threadIdx.x;
    const int lane = tid & 63;
    const int w = tid >> 6;
    const int wr = w >> 1, wc = w & 1;

    // T1: bijective XCD remap, n-fast tile order
    const int nwg = gridDim.x;
    const int orig = blockIdx.x;
    const int q = nwg >> 3, r = nwg & 7;
    const int xcd = orig & 7, idx = orig >> 3;
    const int wg = (xcd < r ? xcd * (q + 1) : r * (q + 1) + (xcd - r) * q) + idx;
    const int bm = (wg / GY) * 128;
    const int bn = (wg % GY) * 128;

    const unsigned short* Ag = A + (long)bm * lda;
    const unsigned short* Bg = Bt + (long)bn * ldb;

    // stage both A and B tiles for K-tile kt into buffer kt&1 (8 insts/thread)
    auto stage = [&](int kt) {
        unsigned short* La = &sh[(kt & 1) * 16384];
        unsigned short* Lb = La + 8192;
#pragma unroll
        for (int u = 0; u < 4; ++u) {
            int c = tid + u * 256;
            int lr = c >> 3, cb = c & 7;
            int sw = (cb ^ (lr & 7)) << 3;
            const unsigned short* ga = Ag + (long)lr * lda + kt * 64 + sw;
            __builtin_amdgcn_global_load_lds(
                (const __attribute__((address_space(1))) void*)ga,
                (__attribute__((address_space(3))) void*)&La[lr * 64 + (cb << 3)], 16, 0, 0);
            const unsigned short* gb = Bg + (long)lr * ldb + kt * 64 + sw;
            __builtin_amdgcn_global_load_lds(
                (const __attribute__((address_space(1))) void*)gb,
                (__attribute__((address_space(3))) void*)&Lb[lr * 64 + (cb << 3)], 16, 0, 0);
        }
    };
    auto ldA = [&](int p, int m, int ks) {
        int row = wr * 64 + m * 16 + (lane & 15);
        int cb = ks * 4 + (lane >> 4);
        return *(const bf16x8*)&sh[p * 16384 + row * 64 + ((cb ^ (row & 7)) << 3)];
    };
    auto ldB = [&](int p, int n, int ks) {
        int row = wc * 64 + n * 16 + (lane & 15);
        int cb = ks * 4 + (lane >> 4);
        return *(const bf16x8*)&sh[p * 16384 + 8192 + row * 64 + ((cb ^ (row & 7)) << 3)];
    };

    f32x4 acc[4][4] = {};

    stage(0); stage(1);
    asm volatile("s_waitcnt vmcnt(8)" ::: "memory");   // kt0 landed, kt1 in flight
    SBAR();

    for (int kt = 0; kt < NK; ++kt) {
        const int p = kt & 1;
        bf16x8 a[4][2], b[4][2];
#pragma unroll
        for (int m = 0; m < 4; ++m) { a[m][0] = ldA(p, m, 0); a[m][1] = ldA(p, m, 1); }
#pragma unroll
        for (int n = 0; n < 4; ++n) { b[n][0] = ldB(p, n, 0); b[n][1] = ldB(p, n, 1); }
        SBAR();                                 // all waves done reading buf p
        if (kt + 2 < NK) stage(kt + 2);         // refill buf p
        LGKM0();
        __builtin_amdgcn_s_setprio(1);
#pragma unroll
        for (int m = 0; m < 4; ++m)
#pragma unroll
            for (int n = 0; n < 4; ++n) {
                MFMA16(acc[m][n], a[m][0], b[n][0]);
                MFMA16(acc[m][n], a[m][1], b[n][1]);
            }
        __builtin_amdgcn_s_setprio(0);
        if (kt + 2 < NK) {
            asm volatile("s_waitcnt vmcnt(8)" ::: "memory");  // kt+1 landed
        } else if (kt + 1 < NK) {
            asm volatile("s_waitcnt vmcnt(0)" ::: "memory");
        }
        SBAR();                                 // publish buf p^1
    }

    // epilogue: C/D layout col=lane&15, row=(lane>>4)*4+j
#pragma unroll
    for (int mi = 0; mi < 4; ++mi) {
        int gr0 = bm + wr * 64 + mi * 16 + (lane >> 4) * 4;
#pragma unroll
        for (int ni = 0; ni < 4; ++ni) {
            int gc = bn + wc * 64 + ni * 16 + (lane & 15);
            float bv = bias ? bias[gc] : 0.f;
#pragma unroll
            for (int j = 0; j < 4; ++j) {
                int gr = gr0 + j;
                if (gr >= M) continue;
                float v = acc[mi][ni][j] + bv;
                if (ACT) v = 0.5f * v * (1.0f + erff(v * 0.70710678118654752f));
                long ci = (long)gr * ldc + gc;
                if (OBF) {
                    ((unsigned short*)C)[ci] = f2bf(v);
                } else {
                    if (resid) v += resid[ci];
                    ((float*)C)[ci] = v;
                }
            }
        }
    }
}

// ---------------------------------------------------------------------------
// fp32 GEMM for the tiny classifier head
// ---------------------------------------------------------------------------
__global__ void gemm_f32_kernel(const float* __restrict__ A,
                                const float* __restrict__ W,
                                const float* __restrict__ bias,
                                float* __restrict__ C,
                                int M, int N, int K) {
    __shared__ float As[16][65];
    __shared__ float Bs[16][65];
    int bm = blockIdx.x * 64, bn = blockIdx.y * 64;
    int t = threadIdx.x;
    int tx = t & 15, ty = t >> 4;
    float acc[4][4] = {};
    for (int k0 = 0; k0 < K; k0 += 16) {
        {
            int ar = bm + (t >> 2);
            int ac = k0 + (t & 3) * 4;
            float4 av = make_float4(0.f, 0.f, 0.f, 0.f);
            if (ar < M) av = *(const float4*)(A + (long)ar * K + ac);
            int kk = (t & 3) * 4, rr = t >> 2;
            As[kk + 0][rr] = av.x; As[kk + 1][rr] = av.y;
            As[kk + 2][rr] = av.z; As[kk + 3][rr] = av.w;
        }
        {
            int wr2 = k0 + (t >> 4);
            int wc2 = bn + (t & 15) * 4;
            float4 wv;
            wv.x = (wc2 + 0 < N) ? W[(long)wr2 * N + wc2 + 0] : 0.f;
            wv.y = (wc2 + 1 < N) ? W[(long)wr2 * N + wc2 + 1] : 0.f;
            wv.z = (wc2 + 2 < N) ? W[(long)wr2 * N + wc2 + 2] : 0.f;
            wv.w = (wc2 + 3 < N) ? W[(long)wr2 * N + wc2 + 3] : 0.f;
            int kr = t >> 4, nc = (t & 15) * 4;
            Bs[kr][nc + 0] = wv.x; Bs[kr][nc + 1] = wv.y;
            Bs[kr][nc + 2] = wv.z; Bs[kr][nc + 3] = wv.w;
        }
        __syncthreads();
#pragma unroll
        for (int kk = 0; kk < 16; ++kk) {
            float a0 = As[kk][ty * 4 + 0], a1 = As[kk][ty * 4 + 1];
            float a2 = As[kk][ty * 4 + 2], a3 = As[kk][ty * 4 + 3];
            float b0 = Bs[kk][tx], b1 = Bs[kk][tx + 16];
            float b2 = Bs[kk][tx + 32], b3 = Bs[kk][tx + 48];
            acc[0][0] += a0 * b0; acc[0][1] += a0 * b1; acc[0][2] += a0 * b2; acc[0][3] += a0 * b3;
            acc[1][0] += a1 * b0; acc[1][1] += a1 * b1; acc[1][2] += a1 * b2; acc[1][3] += a1 * b3;
            acc[2][0] += a2 * b0; acc[2][1] += a2 * b1; acc[2][2] += a2 * b2; acc[2][3] += a2 * b3;
            acc[3][0] += a3 * b0; acc[3][1] += a3 * b1; acc[3][2] += a3 * b2; acc[3][3] += a3 * b3;
        }
        __syncthreads();
    }
#pragma unroll
    for (int i = 0; i < 4; ++i) {
        int r = bm + ty * 4 + i;
        if (r >= M) continue;
#pragma unroll
        for (int j = 0; j < 4; ++j) {
            int c = bn + tx + 16 * j;
            if (c >= N) continue;
            C[(long)r * N + c] = acc[i][j] + (bias ? bias[c] : 0.f);
        }
    }
}

// ---------------------------------------------------------------------------
// Orchestration
// ---------------------------------------------------------------------------
extern "C" void kernel_launch(void* const* d_in, const int* in_sizes, int n_in,
                              void* d_out, int out_size, void* d_ws, size_t ws_size,
                              hipStream_t stream) {
    const float* x        = (const float*)d_in[0];
    const float* conv_w   = (const float*)d_in[1];
    const float* conv_b   = (const float*)d_in[2];
    const float* pos      = (const float*)d_in[3];
    const float* cls_tok  = (const float*)d_in[4];
    const float* ln1_w    = (const float*)d_in[5];
    const float* ln1_b    = (const float*)d_in[6];
    const float* qkv_w    = (const float*)d_in[7];
    const float* out_w    = (const float*)d_in[8];
    const float* out_b    = (const float*)d_in[9];
    const float* ln2_w    = (const float*)d_in[10];
    const float* ln2_b    = (const float*)d_in[11];
    const float* mlp_w1   = (const float*)d_in[12];
    const float* mlp_b1   = (const float*)d_in[13];
    const float* mlp_w2   = (const float*)d_in[14];
    const float* mlp_b2   = (const float*)d_in[15];
    const float* cls_ln_w = (const float*)d_in[16];
    const float* cls_ln_b = (const float*)d_in[17];
    const float* head_w   = (const float*)d_in[18];
    const float* head_b   = (const float*)d_in[19];
    float* out = (float*)d_out;

    char* cur = (char*)d_ws;
    auto alloc = [&](size_t bytes) {
        void* p = cur; cur += (bytes + 255) & ~(size_t)255; return p;
    };
    float*          h      = (float*)alloc((size_t)PAD_ROWS * DIM * 4);
    unsigned short* z_bf   = (unsigned short*)alloc((size_t)PAD_A * DIM * 2);
    unsigned short* qkv_bf = (unsigned short*)alloc((size_t)ROWS * 3 * DIM * 2);
    unsigned short* o_bf   = (unsigned short*)alloc((size_t)PAD_ROWS * DIM * 2);
    unsigned short* m1     = (unsigned short*)alloc((size_t)PAD_ROWS * DIM_MLP * 2);
    unsigned short* qkvwT  = (unsigned short*)alloc((size_t)2304 * 768 * 2);
    unsigned short* owT    = (unsigned short*)alloc((size_t)768 * 768 * 2);
    unsigned short* w1T    = (unsigned short*)alloc((size_t)3072 * 768 * 2);
    unsigned short* w2T    = (unsigned short*)alloc((size_t)768 * 3072 * 2);
    float*          clsz   = (float*)alloc((size_t)BATCH * DIM * 4);

    patch_embed_kernel<<<ROWS, 256, 0, stream>>>(x, conv_w, conv_b, pos, cls_tok, h);

    for (int l = 0; l < DEPTH; ++l) {
        transpose_all_kernel<<<6912, 256, 0, stream>>>(
            qkv_w + (long)l * DIM * 3 * DIM, out_w + (long)l * DIM * DIM,
            mlp_w1 + (long)l * DIM * DIM_MLP, mlp_w2 + (long)l * DIM_MLP * DIM,
            qkvwT, owT, w1T, w2T);

        layernorm_kernel<1><<<ROWS, 256, 0, stream>>>(
            h, DIM, ln1_w + (long)l * DIM, ln1_b + (long)l * DIM, z_bf);

        // qkv = z @ qkv_w   [8224 x 2304], K=768
        gemmd_kernel<12, 0, 1><<<65 * 18, 256, 0, stream>>>(
            z_bf, qkvwT, nullptr, nullptr, qkv_bf, ROWS, 18, DIM, DIM, 3 * DIM);

        // fused attention -> o_bf
        attn_kernel<<<384 * 5, 256, 0, stream>>>(qkv_bf, o_bf);

        // h = o @ out_w + out_b + h   (fp32, in-place residual), K=768
        gemmd_kernel<12, 0, 0><<<65 * 6, 256, 0, stream>>>(
            o_bf, owT, out_b + (long)l * DIM, h, h, ROWS, 6, DIM, DIM, DIM);

        layernorm_kernel<1><<<ROWS, 256, 0, stream>>>(
            h, DIM, ln2_w + (long)l * DIM, ln2_b + (long)l * DIM, z_bf);

        // m1 = gelu(z @ w1 + b1)   [8224 x 3072], K=768
        gemmd_kernel<12, 1, 1><<<65 * 24, 256, 0, stream>>>(
            z_bf, w1T, mlp_b1 + (long)l * DIM_MLP, nullptr, m1, ROWS, 24, DIM, DIM, DIM_MLP);

        // h = m1 @ w2 + b2 + h   (fp32, in-place residual), K=3072
        gemmd_kernel<48, 0, 0><<<65 * 6, 256, 0, stream>>>(
            m1, w2T, mlp_b2 + (long)l * DIM, h, h, ROWS, 6, DIM_MLP, DIM_MLP, DIM);
    }

    layernorm_kernel<0><<<BATCH, 256, 0, stream>>>(
        h, (long)SEQ * DIM, cls_ln_w, cls_ln_b, clsz);
    gemm_f32_kernel<<<dim3(1, 16), 256, 0, stream>>>(
        clsz, head_w, head_b, out, BATCH, NUM_CLASSES, DIM);
}